// Round 10
// baseline (504.506 us; speedup 1.0000x reference)
//
#include <hip/hip_runtime.h>
#include <hip/hip_bf16.h>

#define B_ 4
#define S_ 4096
#define D_ 256

typedef __attribute__((ext_vector_type(8))) short bf16x8;
typedef __attribute__((ext_vector_type(4))) short short4v;
typedef __attribute__((ext_vector_type(4))) float f32x4;

// round-to-nearest-even f32 -> bf16 bits (inputs finite)
static __device__ __forceinline__ unsigned short f2bf(float f) {
    unsigned int u = __float_as_uint(f);
    u += 0x7fffu + ((u >> 16) & 1u);
    return (unsigned short)(u >> 16);
}
static __device__ __forceinline__ float bf2f(unsigned short h) {
    return __uint_as_float(((unsigned int)h) << 16);
}

// ---------------------------------------------------------------------------
// Kernel 1 (unchanged, certified): QKV = X @ W^T + b, f32 in, bf16 out.
// Q,K row-major [b*S+s][256]; V transposed Vt[b][d][s].
// ---------------------------------------------------------------------------
__global__ __launch_bounds__(256) void qkv_proj(
    const float* __restrict__ X, const float* __restrict__ W,
    const float* __restrict__ bias,
    unsigned short* __restrict__ Qb, unsigned short* __restrict__ Kb,
    unsigned short* __restrict__ Vt)
{
    __shared__ __align__(16) unsigned short As[64 * 64];
    __shared__ __align__(16) unsigned short Bs[64 * 64];

    const int tid  = threadIdx.x;
    const int lane = tid & 63;
    const int wid  = tid >> 6;
    const int wm   = wid >> 1, wn = wid & 1;
    const int c    = lane & 15, q4 = lane >> 4;
    const int gm0  = blockIdx.x * 64;
    const int gn0  = blockIdx.y * 64;
    const int sr   = tid >> 2;
    const int sc   = (tid & 3) * 16;

    f32x4 acc[2][2] = {};

    for (int kt = 0; kt < 4; ++kt) {
        const int k0 = kt * 64;
        {
            const float4* ga = (const float4*)(X + (size_t)(gm0 + sr) * D_ + k0 + sc);
            const float4* gb = (const float4*)(W + (size_t)(gn0 + sr) * D_ + k0 + sc);
            float4 a0 = ga[0], a1 = ga[1], a2 = ga[2], a3 = ga[3];
            float4 b0 = gb[0], b1 = gb[1], b2 = gb[2], b3 = gb[3];
            float af[16] = {a0.x,a0.y,a0.z,a0.w, a1.x,a1.y,a1.z,a1.w,
                            a2.x,a2.y,a2.z,a2.w, a3.x,a3.y,a3.z,a3.w};
            float bf[16] = {b0.x,b0.y,b0.z,b0.w, b1.x,b1.y,b1.z,b1.w,
                            b2.x,b2.y,b2.z,b2.w, b3.x,b3.y,b3.z,b3.w};
            bf16x8 av0, av1, bv0, bv1;
            #pragma unroll
            for (int j = 0; j < 8; ++j) {
                av0[j] = (short)f2bf(af[j]);     av1[j] = (short)f2bf(af[8 + j]);
                bv0[j] = (short)f2bf(bf[j]);     bv1[j] = (short)f2bf(bf[8 + j]);
            }
            const int sw = (sr & 7) << 3;
            *(bf16x8*)&As[sr * 64 + ((sc + 0) ^ sw)] = av0;
            *(bf16x8*)&As[sr * 64 + ((sc + 8) ^ sw)] = av1;
            *(bf16x8*)&Bs[sr * 64 + ((sc + 0) ^ sw)] = bv0;
            *(bf16x8*)&Bs[sr * 64 + ((sc + 8) ^ sw)] = bv1;
        }
        __syncthreads();
        const int sw = (c & 7) << 3;
        #pragma unroll
        for (int kk = 0; kk < 64; kk += 32) {
            bf16x8 afr[2], bfr[2];
            #pragma unroll
            for (int mf = 0; mf < 2; ++mf) {
                const int row = wm * 32 + mf * 16 + c;
                afr[mf] = *(const bf16x8*)&As[row * 64 + ((kk + 8 * q4) ^ sw)];
            }
            #pragma unroll
            for (int nf = 0; nf < 2; ++nf) {
                const int row = wn * 32 + nf * 16 + c;
                bfr[nf] = *(const bf16x8*)&Bs[row * 64 + ((kk + 8 * q4) ^ sw)];
            }
            #pragma unroll
            for (int mf = 0; mf < 2; ++mf)
                #pragma unroll
                for (int nf = 0; nf < 2; ++nf)
                    acc[mf][nf] = __builtin_amdgcn_mfma_f32_16x16x32_bf16(
                        afr[mf], bfr[nf], acc[mf][nf], 0, 0, 0);
        }
        __syncthreads();
    }

    const int b  = gm0 >> 12;
    const int s0 = gm0 & 4095;
    #pragma unroll
    for (int mf = 0; mf < 2; ++mf) {
        #pragma unroll
        for (int nf = 0; nf < 2; ++nf) {
            const int e  = gn0 + wn * 32 + nf * 16 + c;
            const float bv = bias[e];
            const int srow0 = s0 + wm * 32 + mf * 16 + 4 * q4;
            if (e < 256) {
                #pragma unroll
                for (int i = 0; i < 4; ++i)
                    Qb[((size_t)b * S_ + srow0 + i) * D_ + e] =
                        f2bf(acc[mf][nf][i] + bv);
            } else if (e < 512) {
                #pragma unroll
                for (int i = 0; i < 4; ++i)
                    Kb[((size_t)b * S_ + srow0 + i) * D_ + (e - 256)] =
                        f2bf(acc[mf][nf][i] + bv);
            } else {
                short4v pv;
                #pragma unroll
                for (int i = 0; i < 4; ++i)
                    pv[i] = (short)f2bf(acc[mf][nf][i] + bv);
                *(short4v*)&Vt[((size_t)(b * D_ + (e - 512))) * S_ + srow0] = pv;
            }
        }
    }
}

// ---------------------------------------------------------------------------
// One flash step over 32 keys. Per-wave LDS slice; NO barriers.
// ---------------------------------------------------------------------------
__device__ __forceinline__ void attn_step(
    const unsigned short* __restrict__ Kbb, const unsigned short* __restrict__ Vtb,
    int kv, const bf16x8 qf[8], int c, int q4,
    unsigned short* plds, float m0[4], float l0[4], f32x4 o[16])
{
    const float C = 0.09016844005556021f;   // log2(e) / sqrt(256)

    f32x4 sacc[2] = {};
    #pragma unroll
    for (int kc = 0; kc < 2; ++kc) {
        const unsigned short* kp = Kbb + (size_t)(kv + kc * 16 + c) * D_ + 8 * q4;
        #pragma unroll
        for (int f = 0; f < 8; ++f) {
            bf16x8 kf = *(const bf16x8*)(kp + f * 32);
            sacc[kc] = __builtin_amdgcn_mfma_f32_16x16x32_bf16(qf[f], kf, sacc[kc], 0, 0, 0);
        }
    }

    float rmax[4];
    #pragma unroll
    for (int i = 0; i < 4; ++i) rmax[i] = fmaxf(sacc[0][i], sacc[1][i]);
    #pragma unroll
    for (int d = 1; d < 16; d <<= 1)
        #pragma unroll
        for (int i = 0; i < 4; ++i)
            rmax[i] = fmaxf(rmax[i], __shfl_xor(rmax[i], d));

    bool grow = false;
    #pragma unroll
    for (int i = 0; i < 4; ++i) grow = grow || (rmax[i] > m0[i]);
    if (__any(grow)) {
        #pragma unroll
        for (int i = 0; i < 4; ++i) {
            const float mn = fmaxf(m0[i], rmax[i]);
            const float corr = exp2f((m0[i] - mn) * C);
            m0[i] = mn;
            l0[i] *= corr;
            #pragma unroll
            for (int dt = 0; dt < 16; ++dt) o[dt][i] *= corr;
        }
    }

    float rsum[4] = {0.f, 0.f, 0.f, 0.f};
    unsigned short pb[2][4];
    #pragma unroll
    for (int kc = 0; kc < 2; ++kc)
        #pragma unroll
        for (int i = 0; i < 4; ++i) {
            const float p = exp2f((sacc[kc][i] - m0[i]) * C);
            const unsigned short us = f2bf(p);
            pb[kc][i] = us;
            rsum[i] += bf2f(us);
        }
    #pragma unroll
    for (int d = 1; d < 16; d <<= 1)
        #pragma unroll
        for (int i = 0; i < 4; ++i) rsum[i] += __shfl_xor(rsum[i], d);
    #pragma unroll
    for (int i = 0; i < 4; ++i) l0[i] += rsum[i];

    #pragma unroll
    for (int kc = 0; kc < 2; ++kc)
        #pragma unroll
        for (int i = 0; i < 4; ++i)
            plds[(4 * q4 + i) * 48 + kc * 16 + c] = pb[kc][i];
    const bf16x8 pf = *(const bf16x8*)&plds[c * 48 + 8 * q4];

    const unsigned short* vp = Vtb + (size_t)c * S_ + kv + 8 * q4;
    #pragma unroll
    for (int dt = 0; dt < 16; ++dt) {
        bf16x8 vf = *(const bf16x8*)(vp + (size_t)dt * 16 * S_);
        o[dt] = __builtin_amdgcn_mfma_f32_16x16x32_bf16(pf, vf, o[dt], 0, 0, 0);
    }
}

// ---------------------------------------------------------------------------
// Kernel 2: flash attention. Block = 512 threads = 8 waves = 4 row-groups x
// 2 KV halves; 64 q-rows/block. Grid 256 x 64 rows = 16384 rows (full B*S).
// 1 block/CU -> 8 waves/CU = 2 waves/SIMD guaranteed.
// Wave (wr, kh): rows [gr0+wr*16, +16), keys [kh*2048, +2048) single chain.
// Two-way merge per row-group via LDS. XCD swizzle pins batch -> XCD pair.
// ---------------------------------------------------------------------------
__global__ __launch_bounds__(512, 2) void attn_fwd(
    const unsigned short* __restrict__ Qb, const unsigned short* __restrict__ Kb,
    const unsigned short* __restrict__ Vt, float* __restrict__ Out)
{
    __shared__ __align__(16) unsigned short Plds[8][16 * 48];  // 12 KiB
    __shared__ __align__(16) float Obuf[4][16][260];           // 66.5 KiB (+4 pad)
    __shared__ float Mbuf[4][16][2];
    __shared__ float Lbuf[4][16][2];

    // --- XCD-aware remap (bijective: 256 = 8 * 32); batch = tile>>6 ---
    const int bid  = blockIdx.x;
    const int xcd  = bid & 7;
    const int tile = (xcd >> 1) * 64 + (bid >> 3) * 2 + (xcd & 1); // [0,256)
    const int gr0  = tile * 64;           // global row base (b*S+s), covers 16384
    const int b    = gr0 >> 12;

    const int tid  = threadIdx.x;
    const int wid  = tid >> 6, lane = tid & 63;
    const int c    = lane & 15, q4 = lane >> 4;
    const int wr   = wid & 3;             // row group [0,4)
    const int kh   = wid >> 2;            // KV half [0,2)
    const int q0   = gr0 + wr * 16;       // first global row of this wave

    bf16x8 qf[8];
    {
        const size_t qbase = ((size_t)(q0 + c)) * D_ + 8 * q4;
        #pragma unroll
        for (int f = 0; f < 8; ++f)
            qf[f] = *(const bf16x8*)&Qb[qbase + f * 32];
    }

    const unsigned short* Kbb = Kb + (size_t)b * S_ * D_;
    const unsigned short* Vtb = Vt + (size_t)b * D_ * S_;

    f32x4 o[16] = {};
    float m0[4], l0[4];
    #pragma unroll
    for (int i = 0; i < 4; ++i) { m0[i] = -1.0e30f; l0[i] = 0.0f; }

    unsigned short* plds = &Plds[wid][0];
    const int kbase = kh * 2048;

    for (int kv = 0; kv < 2048; kv += 32)
        attn_step(Kbb, Vtb, kbase + kv, qf, c, q4, plds, m0, l0, o);

    // ---- two-way merge per row group ----
    const float C = 0.09016844005556021f;

    if (c == 0) {
        #pragma unroll
        for (int i = 0; i < 4; ++i) Mbuf[wr][4 * q4 + i][kh] = m0[i];
    }
    __syncthreads();

    float corr[4];
    #pragma unroll
    for (int i = 0; i < 4; ++i) {
        const float* mr = Mbuf[wr][4 * q4 + i];
        const float gm = fmaxf(mr[0], mr[1]);
        corr[i] = exp2f((m0[i] - gm) * C);
        l0[i] *= corr[i];
    }
    if (c == 0) {
        #pragma unroll
        for (int i = 0; i < 4; ++i) Lbuf[wr][4 * q4 + i][kh] = l0[i];
    }
    #pragma unroll
    for (int dt = 0; dt < 16; ++dt)
        #pragma unroll
        for (int i = 0; i < 4; ++i) o[dt][i] *= corr[i];

    if (kh == 1) {
        #pragma unroll
        for (int dt = 0; dt < 16; ++dt)
            #pragma unroll
            for (int i = 0; i < 4; ++i)
                Obuf[wr][4 * q4 + i][dt * 16 + c] = o[dt][i];
    }
    __syncthreads();

    if (kh == 0) {
        float inv[4];
        #pragma unroll
        for (int i = 0; i < 4; ++i) {
            const float* lr = Lbuf[wr][4 * q4 + i];
            inv[i] = 1.0f / (lr[0] + lr[1]);
        }
        #pragma unroll
        for (int dt = 0; dt < 16; ++dt)
            #pragma unroll
            for (int i = 0; i < 4; ++i) {
                const float v2 = Obuf[wr][4 * q4 + i][dt * 16 + c];
                Out[((size_t)(q0 + 4 * q4 + i)) * D_ + dt * 16 + c] =
                    (o[dt][i] + v2) * inv[i];
            }
    }
}

extern "C" void kernel_launch(void* const* d_in, const int* in_sizes, int n_in,
                              void* d_out, int out_size, void* d_ws, size_t ws_size,
                              hipStream_t stream) {
    (void)out_size; (void)ws_size;
    const void *Xp = nullptr, *Wp = nullptr, *bp = nullptr;
    for (int i = 0; i < n_in; ++i) {
        if      (in_sizes[i] == B_ * S_ * D_) Xp = d_in[i];
        else if (in_sizes[i] == 3 * D_ * D_)  Wp = d_in[i];
        else if (in_sizes[i] == 3 * D_)       bp = d_in[i];
    }
    if (!Xp) Xp = d_in[0];
    if (!Wp) Wp = d_in[1];
    if (!bp) bp = d_in[2];

    float* Out = (float*)d_out;                                 // [B*S][256] f32

    unsigned short* Qb = (unsigned short*)d_ws;                 // 8 MiB
    unsigned short* Kb = Qb + (size_t)B_ * S_ * D_;             // 8 MiB
    unsigned short* Vt = Kb + (size_t)B_ * S_ * D_;             // 8 MiB
    // ws needed: 24 MiB

    dim3 pgrid(256, 12);
    qkv_proj<<<pgrid, 256, 0, stream>>>((const float*)Xp, (const float*)Wp,
                                        (const float*)bp, Qb, Kb, Vt);
    attn_fwd<<<256, 512, 0, stream>>>(Qb, Kb, Vt, Out);
}

// Round 11
// 244.142 us; speedup vs baseline: 2.0664x; 2.0664x over previous
//
#include <hip/hip_runtime.h>
#include <hip/hip_bf16.h>

#define B_ 4
#define S_ 4096
#define D_ 256

typedef __attribute__((ext_vector_type(8))) short bf16x8;
typedef __attribute__((ext_vector_type(4))) short short4v;
typedef __attribute__((ext_vector_type(4))) float f32x4;

// round-to-nearest-even f32 -> bf16 bits (inputs finite)
static __device__ __forceinline__ unsigned short f2bf(float f) {
    unsigned int u = __float_as_uint(f);
    u += 0x7fffu + ((u >> 16) & 1u);
    return (unsigned short)(u >> 16);
}
static __device__ __forceinline__ float bf2f(unsigned short h) {
    return __uint_as_float(((unsigned int)h) << 16);
}

// ---------------------------------------------------------------------------
// Kernel 1 (unchanged, certified): QKV = X @ W^T + b, f32 in, bf16 out.
// Q,K row-major [b*S+s][256]; V transposed Vt[b][d][s].
// ---------------------------------------------------------------------------
__global__ __launch_bounds__(256) void qkv_proj(
    const float* __restrict__ X, const float* __restrict__ W,
    const float* __restrict__ bias,
    unsigned short* __restrict__ Qb, unsigned short* __restrict__ Kb,
    unsigned short* __restrict__ Vt)
{
    __shared__ __align__(16) unsigned short As[64 * 64];
    __shared__ __align__(16) unsigned short Bs[64 * 64];

    const int tid  = threadIdx.x;
    const int lane = tid & 63;
    const int wid  = tid >> 6;
    const int wm   = wid >> 1, wn = wid & 1;
    const int c    = lane & 15, q4 = lane >> 4;
    const int gm0  = blockIdx.x * 64;
    const int gn0  = blockIdx.y * 64;
    const int sr   = tid >> 2;
    const int sc   = (tid & 3) * 16;

    f32x4 acc[2][2] = {};

    for (int kt = 0; kt < 4; ++kt) {
        const int k0 = kt * 64;
        {
            const float4* ga = (const float4*)(X + (size_t)(gm0 + sr) * D_ + k0 + sc);
            const float4* gb = (const float4*)(W + (size_t)(gn0 + sr) * D_ + k0 + sc);
            float4 a0 = ga[0], a1 = ga[1], a2 = ga[2], a3 = ga[3];
            float4 b0 = gb[0], b1 = gb[1], b2 = gb[2], b3 = gb[3];
            float af[16] = {a0.x,a0.y,a0.z,a0.w, a1.x,a1.y,a1.z,a1.w,
                            a2.x,a2.y,a2.z,a2.w, a3.x,a3.y,a3.z,a3.w};
            float bf[16] = {b0.x,b0.y,b0.z,b0.w, b1.x,b1.y,b1.z,b1.w,
                            b2.x,b2.y,b2.z,b2.w, b3.x,b3.y,b3.z,b3.w};
            bf16x8 av0, av1, bv0, bv1;
            #pragma unroll
            for (int j = 0; j < 8; ++j) {
                av0[j] = (short)f2bf(af[j]);     av1[j] = (short)f2bf(af[8 + j]);
                bv0[j] = (short)f2bf(bf[j]);     bv1[j] = (short)f2bf(bf[8 + j]);
            }
            const int sw = (sr & 7) << 3;
            *(bf16x8*)&As[sr * 64 + ((sc + 0) ^ sw)] = av0;
            *(bf16x8*)&As[sr * 64 + ((sc + 8) ^ sw)] = av1;
            *(bf16x8*)&Bs[sr * 64 + ((sc + 0) ^ sw)] = bv0;
            *(bf16x8*)&Bs[sr * 64 + ((sc + 8) ^ sw)] = bv1;
        }
        __syncthreads();
        const int sw = (c & 7) << 3;
        #pragma unroll
        for (int kk = 0; kk < 64; kk += 32) {
            bf16x8 afr[2], bfr[2];
            #pragma unroll
            for (int mf = 0; mf < 2; ++mf) {
                const int row = wm * 32 + mf * 16 + c;
                afr[mf] = *(const bf16x8*)&As[row * 64 + ((kk + 8 * q4) ^ sw)];
            }
            #pragma unroll
            for (int nf = 0; nf < 2; ++nf) {
                const int row = wn * 32 + nf * 16 + c;
                bfr[nf] = *(const bf16x8*)&Bs[row * 64 + ((kk + 8 * q4) ^ sw)];
            }
            #pragma unroll
            for (int mf = 0; mf < 2; ++mf)
                #pragma unroll
                for (int nf = 0; nf < 2; ++nf)
                    acc[mf][nf] = __builtin_amdgcn_mfma_f32_16x16x32_bf16(
                        afr[mf], bfr[nf], acc[mf][nf], 0, 0, 0);
        }
        __syncthreads();
    }

    const int b  = gm0 >> 12;
    const int s0 = gm0 & 4095;
    #pragma unroll
    for (int mf = 0; mf < 2; ++mf) {
        #pragma unroll
        for (int nf = 0; nf < 2; ++nf) {
            const int e  = gn0 + wn * 32 + nf * 16 + c;
            const float bv = bias[e];
            const int srow0 = s0 + wm * 32 + mf * 16 + 4 * q4;
            if (e < 256) {
                #pragma unroll
                for (int i = 0; i < 4; ++i)
                    Qb[((size_t)b * S_ + srow0 + i) * D_ + e] =
                        f2bf(acc[mf][nf][i] + bv);
            } else if (e < 512) {
                #pragma unroll
                for (int i = 0; i < 4; ++i)
                    Kb[((size_t)b * S_ + srow0 + i) * D_ + (e - 256)] =
                        f2bf(acc[mf][nf][i] + bv);
            } else {
                short4v pv;
                #pragma unroll
                for (int i = 0; i < 4; ++i)
                    pv[i] = (short)f2bf(acc[mf][nf][i] + bv);
                *(short4v*)&Vt[((size_t)(b * D_ + (e - 512))) * S_ + srow0] = pv;
            }
        }
    }
}

// ---------------------------------------------------------------------------
// One flash step over 32 keys, fragments from LDS-staged tiles.
// K tile: [32 rows][512B] with byte ^ ((row&7)<<4) swizzle.
// V tile: [256 d][80B padded rows], data in bytes 0..63 (32 keys x bf16).
// Per-wave Plds slice, no barriers inside. Softmax/P path certified r6-r10.
// ---------------------------------------------------------------------------
__device__ __forceinline__ void attn_step_lds(
    const char* Ksb, const char* Vsb,
    const bf16x8 qf[8], int c, int q4, int swzK,
    unsigned short* plds, float m0[4], float l0[4], f32x4 o[16])
{
    const float C = 0.09016844005556021f;   // log2(e) / sqrt(256)

    f32x4 sacc[2] = {};
    #pragma unroll
    for (int kc = 0; kc < 2; ++kc) {
        const int rowb = (kc * 16 + c) * 512;
        #pragma unroll
        for (int f = 0; f < 8; ++f) {
            bf16x8 kf = *(const bf16x8*)(Ksb + rowb + ((q4 * 16 + f * 64) ^ swzK));
            sacc[kc] = __builtin_amdgcn_mfma_f32_16x16x32_bf16(qf[f], kf, sacc[kc], 0, 0, 0);
        }
    }

    float rmax[4];
    #pragma unroll
    for (int i = 0; i < 4; ++i) rmax[i] = fmaxf(sacc[0][i], sacc[1][i]);
    #pragma unroll
    for (int d = 1; d < 16; d <<= 1)
        #pragma unroll
        for (int i = 0; i < 4; ++i)
            rmax[i] = fmaxf(rmax[i], __shfl_xor(rmax[i], d));

    bool grow = false;
    #pragma unroll
    for (int i = 0; i < 4; ++i) grow = grow || (rmax[i] > m0[i]);
    if (__any(grow)) {
        #pragma unroll
        for (int i = 0; i < 4; ++i) {
            const float mn = fmaxf(m0[i], rmax[i]);
            const float corr = exp2f((m0[i] - mn) * C);
            m0[i] = mn;
            l0[i] *= corr;
            #pragma unroll
            for (int dt = 0; dt < 16; ++dt) o[dt][i] *= corr;
        }
    }

    float rsum[4] = {0.f, 0.f, 0.f, 0.f};
    unsigned short pb[2][4];
    #pragma unroll
    for (int kc = 0; kc < 2; ++kc)
        #pragma unroll
        for (int i = 0; i < 4; ++i) {
            const float p = exp2f((sacc[kc][i] - m0[i]) * C);
            const unsigned short us = f2bf(p);
            pb[kc][i] = us;
            rsum[i] += bf2f(us);
        }
    #pragma unroll
    for (int d = 1; d < 16; d <<= 1)
        #pragma unroll
        for (int i = 0; i < 4; ++i) rsum[i] += __shfl_xor(rsum[i], d);
    #pragma unroll
    for (int i = 0; i < 4; ++i) l0[i] += rsum[i];

    #pragma unroll
    for (int kc = 0; kc < 2; ++kc)
        #pragma unroll
        for (int i = 0; i < 4; ++i)
            plds[(4 * q4 + i) * 48 + kc * 16 + c] = pb[kc][i];
    const bf16x8 pf = *(const bf16x8*)&plds[c * 48 + 8 * q4];

    #pragma unroll
    for (int dt = 0; dt < 16; ++dt) {
        bf16x8 vf = *(const bf16x8*)(Vsb + (dt * 16 + c) * 80 + q4 * 16);
        o[dt] = __builtin_amdgcn_mfma_f32_16x16x32_bf16(pf, vf, o[dt], 0, 0, 0);
    }
}

// ---------------------------------------------------------------------------
// Kernel 2: flash attention with block-cooperative double-buffered LDS
// staging. Block = 512 thr = 8 waves = 4 row-groups x 2 KV halves; 64 rows.
// Per step: all threads stage next K/V tiles (both halves, 64KB) while
// computing current from LDS. 1 barrier/step. Grid 256 (XCD-swizzled).
// LDS map (bytes): [0,147456) 2 x {K0 16K | K1 16K | V0 20K | V1 20K}
//                  [147456,159744) Plds 8x1536 | [159744..] Mbuf,Lbuf
//                  Obuf[4][16][260] f32 aliases [0,66560) after the loop.
// ---------------------------------------------------------------------------
__global__ __launch_bounds__(512) void attn_fwd(
    const unsigned short* __restrict__ Qb, const unsigned short* __restrict__ Kb,
    const unsigned short* __restrict__ Vt, float* __restrict__ Out)
{
    __shared__ __align__(16) char smem[160768];

    // --- XCD-aware remap (bijective: 256 = 8 * 32) ---
    const int bid  = blockIdx.x;
    const int xcd  = bid & 7;
    const int tile = (xcd >> 1) * 64 + (bid >> 3) * 2 + (xcd & 1);
    const int gr0  = tile * 64;
    const int b    = gr0 >> 12;

    const int tid  = threadIdx.x;
    const int wid  = tid >> 6, lane = tid & 63;
    const int c    = lane & 15, q4 = lane >> 4;
    const int wr   = wid & 3;             // row group [0,4)
    const int kh   = wid >> 2;            // KV half [0,2)
    const int q0   = gr0 + wr * 16;
    const int swzK = (c & 7) << 4;

    bf16x8 qf[8];
    {
        const size_t qbase = ((size_t)(q0 + c)) * D_ + 8 * q4;
        #pragma unroll
        for (int f = 0; f < 8; ++f)
            qf[f] = *(const bf16x8*)&Qb[qbase + f * 32];
    }

    const unsigned short* Kbb = Kb + (size_t)b * S_ * D_;
    const unsigned short* Vtb = Vt + (size_t)b * D_ * S_;

    // --- staging roles: thread t stages half sh; 64B of K and 64B of V ---
    const int sh    = tid >> 8;           // staged half
    const int st    = tid & 255;
    const int krow  = st >> 3;            // K tile row 0..31
    const int kcolB = (st & 7) * 64;      // byte col within 512B row
    const int kswz  = (krow & 7) << 4;
    const unsigned short* kg = Kbb + (size_t)(sh * 2048 + krow) * D_ + (kcolB >> 1);
    const unsigned short* vg = Vtb + (size_t)st * S_ + sh * 2048;
    char* ksw0 = smem + sh * 16384 + krow * 512;
    char* vsw0 = smem + 32768 + sh * 20480 + st * 80;

    unsigned short* plds = (unsigned short*)(smem + 147456 + wid * 1536);
    float* Mbuf = (float*)(smem + 159744);   // [ (wr*16+r)*2 + kh ]
    float* Lbuf = (float*)(smem + 160256);

    f32x4 o[16] = {};
    float m0[4], l0[4];
    #pragma unroll
    for (int i = 0; i < 4; ++i) { m0[i] = -1.0e30f; l0[i] = 0.0f; }

    // --- prologue: stage tile 0 into buffer 0 ---
    {
        bf16x8 ka[4], va[4];
        #pragma unroll
        for (int j = 0; j < 4; ++j) { ka[j] = *(const bf16x8*)(kg + j * 8);
                                      va[j] = *(const bf16x8*)(vg + j * 8); }
        #pragma unroll
        for (int j = 0; j < 4; ++j) {
            *(bf16x8*)(ksw0 + ((kcolB + j * 16) ^ kswz)) = ka[j];
            *(bf16x8*)(vsw0 + j * 16) = va[j];
        }
    }
    __syncthreads();

    const int NS = 64;                    // steps of 32 keys over 2048
    int p = 0;
    for (int s = 0; s < NS; ++s) {
        bf16x8 ka[4], va[4];
        const int nx = s + 1;
        if (nx < NS) {
            const unsigned short* kgs = kg + (size_t)nx * 32 * D_;
            const unsigned short* vgs = vg + nx * 32;
            #pragma unroll
            for (int j = 0; j < 4; ++j) { ka[j] = *(const bf16x8*)(kgs + j * 8);
                                          va[j] = *(const bf16x8*)(vgs + j * 8); }
        }

        const char* Ksb = smem + p * 73728 + kh * 16384;
        const char* Vsb = smem + p * 73728 + 32768 + kh * 20480;
        attn_step_lds(Ksb, Vsb, qf, c, q4, swzK, plds, m0, l0, o);

        if (nx < NS) {
            char* kd = ksw0 + (p ^ 1) * 73728;
            char* vd = vsw0 + (p ^ 1) * 73728;
            #pragma unroll
            for (int j = 0; j < 4; ++j) {
                *(bf16x8*)(kd + ((kcolB + j * 16) ^ kswz)) = ka[j];
                *(bf16x8*)(vd + j * 16) = va[j];
            }
        }
        __syncthreads();
        p ^= 1;
    }

    // ---- two-way merge per row group (certified r10 logic) ----
    const float C = 0.09016844005556021f;

    if (c == 0) {
        #pragma unroll
        for (int i = 0; i < 4; ++i) Mbuf[(wr * 16 + 4 * q4 + i) * 2 + kh] = m0[i];
    }
    __syncthreads();

    float corr[4];
    #pragma unroll
    for (int i = 0; i < 4; ++i) {
        const float* mr = &Mbuf[(wr * 16 + 4 * q4 + i) * 2];
        const float gm = fmaxf(mr[0], mr[1]);
        corr[i] = exp2f((m0[i] - gm) * C);
        l0[i] *= corr[i];
    }
    if (c == 0) {
        #pragma unroll
        for (int i = 0; i < 4; ++i) Lbuf[(wr * 16 + 4 * q4 + i) * 2 + kh] = l0[i];
    }
    #pragma unroll
    for (int dt = 0; dt < 16; ++dt)
        #pragma unroll
        for (int i = 0; i < 4; ++i) o[dt][i] *= corr[i];

    float* Obuf = (float*)smem;           // [4][16][260], aliases KV buffers
    if (kh == 1) {
        #pragma unroll
        for (int dt = 0; dt < 16; ++dt)
            #pragma unroll
            for (int i = 0; i < 4; ++i)
                Obuf[(wr * 16 + 4 * q4 + i) * 260 + dt * 16 + c] = o[dt][i];
    }
    __syncthreads();

    if (kh == 0) {
        float inv[4];
        #pragma unroll
        for (int i = 0; i < 4; ++i) {
            const float* lr = &Lbuf[(wr * 16 + 4 * q4 + i) * 2];
            inv[i] = 1.0f / (lr[0] + lr[1]);
        }
        #pragma unroll
        for (int dt = 0; dt < 16; ++dt)
            #pragma unroll
            for (int i = 0; i < 4; ++i) {
                const float v2 = Obuf[(wr * 16 + 4 * q4 + i) * 260 + dt * 16 + c];
                Out[((size_t)(q0 + 4 * q4 + i)) * D_ + dt * 16 + c] =
                    (o[dt][i] + v2) * inv[i];
            }
    }
}

extern "C" void kernel_launch(void* const* d_in, const int* in_sizes, int n_in,
                              void* d_out, int out_size, void* d_ws, size_t ws_size,
                              hipStream_t stream) {
    (void)out_size; (void)ws_size;
    const void *Xp = nullptr, *Wp = nullptr, *bp = nullptr;
    for (int i = 0; i < n_in; ++i) {
        if      (in_sizes[i] == B_ * S_ * D_) Xp = d_in[i];
        else if (in_sizes[i] == 3 * D_ * D_)  Wp = d_in[i];
        else if (in_sizes[i] == 3 * D_)       bp = d_in[i];
    }
    if (!Xp) Xp = d_in[0];
    if (!Wp) Wp = d_in[1];
    if (!bp) bp = d_in[2];

    float* Out = (float*)d_out;                                 // [B*S][256] f32

    unsigned short* Qb = (unsigned short*)d_ws;                 // 8 MiB
    unsigned short* Kb = Qb + (size_t)B_ * S_ * D_;             // 8 MiB
    unsigned short* Vt = Kb + (size_t)B_ * S_ * D_;             // 8 MiB
    // ws needed: 24 MiB

    dim3 pgrid(256, 12);
    qkv_proj<<<pgrid, 256, 0, stream>>>((const float*)Xp, (const float*)Wp,
                                        (const float*)bp, Qb, Kb, Vt);
    attn_fwd<<<256, 512, 0, stream>>>(Qb, Kb, Vt, Out);
}

// Round 12
// 242.021 us; speedup vs baseline: 2.0846x; 1.0088x over previous
//
#include <hip/hip_runtime.h>
#include <hip/hip_bf16.h>

#define B_ 4
#define S_ 4096
#define D_ 256

typedef __attribute__((ext_vector_type(8))) short bf16x8;
typedef __attribute__((ext_vector_type(4))) short short4v;
typedef __attribute__((ext_vector_type(4))) float f32x4;
typedef __attribute__((ext_vector_type(16))) float f32x16;

// round-to-nearest-even f32 -> bf16 bits (inputs finite)
static __device__ __forceinline__ unsigned short f2bf(float f) {
    unsigned int u = __float_as_uint(f);
    u += 0x7fffu + ((u >> 16) & 1u);
    return (unsigned short)(u >> 16);
}
static __device__ __forceinline__ float bf2f(unsigned short h) {
    return __uint_as_float(((unsigned int)h) << 16);
}

// ---------------------------------------------------------------------------
// Kernel 1 (unchanged, certified): QKV = X @ W^T + b, f32 in, bf16 out.
// Q,K row-major [b*S+s][256]; V transposed Vt[b][d][s].
// ---------------------------------------------------------------------------
__global__ __launch_bounds__(256) void qkv_proj(
    const float* __restrict__ X, const float* __restrict__ W,
    const float* __restrict__ bias,
    unsigned short* __restrict__ Qb, unsigned short* __restrict__ Kb,
    unsigned short* __restrict__ Vt)
{
    __shared__ __align__(16) unsigned short As[64 * 64];
    __shared__ __align__(16) unsigned short Bs[64 * 64];

    const int tid  = threadIdx.x;
    const int lane = tid & 63;
    const int wid  = tid >> 6;
    const int wm   = wid >> 1, wn = wid & 1;
    const int c    = lane & 15, q4 = lane >> 4;
    const int gm0  = blockIdx.x * 64;
    const int gn0  = blockIdx.y * 64;
    const int sr   = tid >> 2;
    const int sc   = (tid & 3) * 16;

    f32x4 acc[2][2] = {};

    for (int kt = 0; kt < 4; ++kt) {
        const int k0 = kt * 64;
        {
            const float4* ga = (const float4*)(X + (size_t)(gm0 + sr) * D_ + k0 + sc);
            const float4* gb = (const float4*)(W + (size_t)(gn0 + sr) * D_ + k0 + sc);
            float4 a0 = ga[0], a1 = ga[1], a2 = ga[2], a3 = ga[3];
            float4 b0 = gb[0], b1 = gb[1], b2 = gb[2], b3 = gb[3];
            float af[16] = {a0.x,a0.y,a0.z,a0.w, a1.x,a1.y,a1.z,a1.w,
                            a2.x,a2.y,a2.z,a2.w, a3.x,a3.y,a3.z,a3.w};
            float bf[16] = {b0.x,b0.y,b0.z,b0.w, b1.x,b1.y,b1.z,b1.w,
                            b2.x,b2.y,b2.z,b2.w, b3.x,b3.y,b3.z,b3.w};
            bf16x8 av0, av1, bv0, bv1;
            #pragma unroll
            for (int j = 0; j < 8; ++j) {
                av0[j] = (short)f2bf(af[j]);     av1[j] = (short)f2bf(af[8 + j]);
                bv0[j] = (short)f2bf(bf[j]);     bv1[j] = (short)f2bf(bf[8 + j]);
            }
            const int sw = (sr & 7) << 3;
            *(bf16x8*)&As[sr * 64 + ((sc + 0) ^ sw)] = av0;
            *(bf16x8*)&As[sr * 64 + ((sc + 8) ^ sw)] = av1;
            *(bf16x8*)&Bs[sr * 64 + ((sc + 0) ^ sw)] = bv0;
            *(bf16x8*)&Bs[sr * 64 + ((sc + 8) ^ sw)] = bv1;
        }
        __syncthreads();
        const int sw = (c & 7) << 3;
        #pragma unroll
        for (int kk = 0; kk < 64; kk += 32) {
            bf16x8 afr[2], bfr[2];
            #pragma unroll
            for (int mf = 0; mf < 2; ++mf) {
                const int row = wm * 32 + mf * 16 + c;
                afr[mf] = *(const bf16x8*)&As[row * 64 + ((kk + 8 * q4) ^ sw)];
            }
            #pragma unroll
            for (int nf = 0; nf < 2; ++nf) {
                const int row = wn * 32 + nf * 16 + c;
                bfr[nf] = *(const bf16x8*)&Bs[row * 64 + ((kk + 8 * q4) ^ sw)];
            }
            #pragma unroll
            for (int mf = 0; mf < 2; ++mf)
                #pragma unroll
                for (int nf = 0; nf < 2; ++nf)
                    acc[mf][nf] = __builtin_amdgcn_mfma_f32_16x16x32_bf16(
                        afr[mf], bfr[nf], acc[mf][nf], 0, 0, 0);
        }
        __syncthreads();
    }

    const int b  = gm0 >> 12;
    const int s0 = gm0 & 4095;
    #pragma unroll
    for (int mf = 0; mf < 2; ++mf) {
        #pragma unroll
        for (int nf = 0; nf < 2; ++nf) {
            const int e  = gn0 + wn * 32 + nf * 16 + c;
            const float bv = bias[e];
            const int srow0 = s0 + wm * 32 + mf * 16 + 4 * q4;
            if (e < 256) {
                #pragma unroll
                for (int i = 0; i < 4; ++i)
                    Qb[((size_t)b * S_ + srow0 + i) * D_ + e] =
                        f2bf(acc[mf][nf][i] + bv);
            } else if (e < 512) {
                #pragma unroll
                for (int i = 0; i < 4; ++i)
                    Kb[((size_t)b * S_ + srow0 + i) * D_ + (e - 256)] =
                        f2bf(acc[mf][nf][i] + bv);
            } else {
                short4v pv;
                #pragma unroll
                for (int i = 0; i < 4; ++i)
                    pv[i] = (short)f2bf(acc[mf][nf][i] + bv);
                *(short4v*)&Vt[((size_t)(b * D_ + (e - 512))) * S_ + srow0] = pv;
            }
        }
    }
}

// ---------------------------------------------------------------------------
// Kernel 2: flash attention, 32x32x16 MFMA, swapped QK^T, in-register
// softmax. Block = 256 thr = 4 waves = 2 row-groups(32 rows) x 2 key-halves.
// 64 rows/block, grid 256 (XCD swizzled). LDS: double-buffered K/V staging
// (tiles identical to r11: K 32x512B XOR-swizzled, V 256x80B padded).
// Lane state: q = lane&31 (both hi=lane>>5 halves duplicate m,l).
// QK: sacc = mfma(K,Q) -> lane holds 16 scores (keys crow(r,hi)) of its q.
// P assembly: pack bf16 pairs, one shfl_xor(32) per pack, table per hi.
// ---------------------------------------------------------------------------
__global__ __launch_bounds__(256, 1) void attn_fwd(
    const unsigned short* __restrict__ Qb, const unsigned short* __restrict__ Kb,
    const unsigned short* __restrict__ Vt, float* __restrict__ Out)
{
    __shared__ __align__(16) char smem[148480];
    // [0,147456): 2 buffers x {K h0 16K | K h1 16K | V h0 20K | V h1 20K}
    // [147456): Mbuf f32[64][2]; [147968): Lbuf f32[64][2]
    // Obuf f32[64][260] aliases [0,66560) after the loop.

    const int bid  = blockIdx.x;
    const int xcd  = bid & 7;
    const int tile = (xcd >> 1) * 64 + (bid >> 3) * 2 + (xcd & 1); // [0,256)
    const int gr0  = tile * 64;
    const int b    = gr0 >> 12;

    const int tid  = threadIdx.x;
    const int wid  = tid >> 6, lane = tid & 63;
    const int ql   = lane & 31, hi = lane >> 5;
    const int rg   = wid & 1;             // row group (32 rows)
    const int kh   = wid >> 1;            // key half
    const float C  = 0.09016844005556021f;   // log2(e)/sqrt(256)
    const float THR = 40.0f;              // defer-max threshold (raw score)

    // Q fragments (B operand): q = gr0 + rg*32 + ql; per mfma m: d = m*16+8*hi+j
    bf16x8 qf[16];
    {
        const size_t qrow = (size_t)(gr0 + rg * 32 + ql) * D_ + 8 * hi;
        #pragma unroll
        for (int m = 0; m < 16; ++m)
            qf[m] = *(const bf16x8*)&Qb[qrow + m * 16];
    }

    const unsigned short* Kbb = Kb + (size_t)b * S_ * D_;
    const unsigned short* Vtb = Vt + (size_t)b * D_ * S_;

    // staging roles: sh = tid>>7 (key half), st = tid&127.
    // K: 128B of row krow=st>>2 at col (st&3)*128. V: rows st and st+128, 64B.
    const int sh    = tid >> 7;
    const int st    = tid & 127;
    const int krow  = st >> 2;
    const int kcolB = (st & 3) * 128;
    const int kswz  = (krow & 7) << 4;
    const unsigned short* kg  = Kbb + (size_t)(sh * 2048 + krow) * D_ + (kcolB >> 1);
    const unsigned short* vg0 = Vtb + (size_t)st * S_ + sh * 2048;
    const unsigned short* vg1 = vg0 + (size_t)128 * S_;
    char* ksw0 = smem + sh * 16384 + krow * 512;
    char* vsw0 = smem + 32768 + sh * 20480 + st * 80;
    char* vsw1 = vsw0 + 128 * 80;

    float* Mbuf = (float*)(smem + 147456);
    float* Lbuf = (float*)(smem + 147968);

    f32x16 o[8] = {};
    float m0 = -1.0e30f, l0 = 0.0f;

    // --- prologue: stage tile 0 into buffer 0 ---
    {
        bf16x8 ka[8], va[8];
        #pragma unroll
        for (int t = 0; t < 8; ++t) ka[t] = *(const bf16x8*)(kg + t * 8);
        #pragma unroll
        for (int t = 0; t < 4; ++t) { va[t]     = *(const bf16x8*)(vg0 + t * 8);
                                      va[t + 4] = *(const bf16x8*)(vg1 + t * 8); }
        #pragma unroll
        for (int t = 0; t < 8; ++t)
            *(bf16x8*)(ksw0 + ((kcolB + t * 16) ^ kswz)) = ka[t];
        #pragma unroll
        for (int t = 0; t < 4; ++t) { *(bf16x8*)(vsw0 + t * 16) = va[t];
                                      *(bf16x8*)(vsw1 + t * 16) = va[t + 4]; }
    }
    __syncthreads();

    const int NS = 64;
    int p = 0;
    const int kswzR = (ql & 7) << 4;

    for (int s = 0; s < NS; ++s) {
        // prefetch next tile into registers (T14)
        bf16x8 ka[8], va[8];
        const int nx = s + 1;
        if (nx < NS) {
            const unsigned short* kgs  = kg  + (size_t)nx * 32 * D_;
            const unsigned short* vgs0 = vg0 + nx * 32;
            const unsigned short* vgs1 = vg1 + nx * 32;
            #pragma unroll
            for (int t = 0; t < 8; ++t) ka[t] = *(const bf16x8*)(kgs + t * 8);
            #pragma unroll
            for (int t = 0; t < 4; ++t) { va[t]     = *(const bf16x8*)(vgs0 + t * 8);
                                          va[t + 4] = *(const bf16x8*)(vgs1 + t * 8); }
        }

        const char* Ksb = smem + p * 73728 + kh * 16384;
        const char* Vsb = smem + p * 73728 + 32768 + kh * 20480;

        // ---- QK^T (swapped): sacc[r] = S[key crow(r,hi)][q=ql] ----
        f32x16 sacc = {};
        #pragma unroll
        for (int m = 0; m < 16; ++m) {
            bf16x8 kf = *(const bf16x8*)(Ksb + ql * 512 + ((m * 32 + hi * 16) ^ kswzR));
            sacc = __builtin_amdgcn_mfma_f32_32x32x16_bf16(kf, qf[m], sacc, 0, 0, 0);
        }

        // ---- row max (q = ql): 15 local + 1 cross-hi ----
        float rmax = sacc[0];
        #pragma unroll
        for (int r = 1; r < 16; ++r) rmax = fmaxf(rmax, sacc[r]);
        rmax = fmaxf(rmax, __shfl_xor(rmax, 32));

        if (__any(rmax > m0 + THR)) {
            const float mn = fmaxf(m0, rmax);
            const float corr = exp2f((m0 - mn) * C);
            m0 = mn;
            l0 *= corr;
            #pragma unroll
            for (int r = 0; r < 16; ++r) {
                const int row = (r & 3) + 8 * (r >> 2) + 4 * hi;
                const float cr = __shfl(corr, row);
                #pragma unroll
                for (int ch = 0; ch < 8; ++ch) o[ch][r] *= cr;
            }
        }

        // ---- P = exp(S - m0) (bounded by 2^(THR*C)), pack bf16 pairs ----
        float rsum = 0.f;
        unsigned int pk[8];
        #pragma unroll
        for (int t = 0; t < 8; ++t) {
            const unsigned short u0 = f2bf(exp2f((sacc[2 * t]     - m0) * C));
            const unsigned short u1 = f2bf(exp2f((sacc[2 * t + 1] - m0) * C));
            rsum += bf2f(u0) + bf2f(u1);
            pk[t] = (unsigned int)u0 | ((unsigned int)u1 << 16);
        }
        rsum += __shfl_xor(rsum, 32);
        l0 += rsum;

        unsigned int Ap[8];
        #pragma unroll
        for (int t = 0; t < 8; ++t) Ap[t] = __shfl_xor(pk[t], 32);

        // ---- assemble P A-fragments (keys kc*16+8*hi+j for j=0..7) ----
        union U { unsigned int w[4]; bf16x8 v; };
        U pa0, pa1;
        if (hi == 0) {
            pa0.w[0] = pk[0]; pa0.w[1] = pk[1]; pa0.w[2] = Ap[0]; pa0.w[3] = Ap[1];
            pa1.w[0] = pk[4]; pa1.w[1] = pk[5]; pa1.w[2] = Ap[4]; pa1.w[3] = Ap[5];
        } else {
            pa0.w[0] = Ap[2]; pa0.w[1] = Ap[3]; pa0.w[2] = pk[2]; pa0.w[3] = pk[3];
            pa1.w[0] = Ap[6]; pa1.w[1] = Ap[7]; pa1.w[2] = pk[6]; pa1.w[3] = pk[7];
        }

        // ---- O += P @ V : 8 d-chunks x 2 key-sub-tiles ----
        #pragma unroll
        for (int ch = 0; ch < 8; ++ch) {
            const char* vrow = Vsb + (ch * 32 + ql) * 80 + hi * 16;
            bf16x8 vf0 = *(const bf16x8*)(vrow);
            bf16x8 vf1 = *(const bf16x8*)(vrow + 32);
            o[ch] = __builtin_amdgcn_mfma_f32_32x32x16_bf16(pa0.v, vf0, o[ch], 0, 0, 0);
            o[ch] = __builtin_amdgcn_mfma_f32_32x32x16_bf16(pa1.v, vf1, o[ch], 0, 0, 0);
        }

        // ---- write prefetched tile to the other buffer ----
        if (nx < NS) {
            char* kd  = ksw0 + (p ^ 1) * 73728;
            char* vd0 = vsw0 + (p ^ 1) * 73728;
            char* vd1 = vsw1 + (p ^ 1) * 73728;
            #pragma unroll
            for (int t = 0; t < 8; ++t)
                *(bf16x8*)(kd + ((kcolB + t * 16) ^ kswz)) = ka[t];
            #pragma unroll
            for (int t = 0; t < 4; ++t) { *(bf16x8*)(vd0 + t * 16) = va[t];
                                          *(bf16x8*)(vd1 + t * 16) = va[t + 4]; }
        }
        __syncthreads();
        p ^= 1;
    }

    // ---- merge across key halves ----
    const int qidx = rg * 32 + ql;
    if (hi == 0) Mbuf[qidx * 2 + kh] = m0;
    __syncthreads();

    {
        const float gm = fmaxf(Mbuf[qidx * 2], Mbuf[qidx * 2 + 1]);
        l0 *= exp2f((m0 - gm) * C);
    }
    if (hi == 0) Lbuf[qidx * 2 + kh] = l0;

    float cr[16];
    #pragma unroll
    for (int r = 0; r < 16; ++r) {
        const int row  = (r & 3) + 8 * (r >> 2) + 4 * hi;
        const int ridx = rg * 32 + row;
        const float mw  = Mbuf[ridx * 2 + kh];
        const float gmr = fmaxf(Mbuf[ridx * 2], Mbuf[ridx * 2 + 1]);
        cr[r] = exp2f((mw - gmr) * C);
    }
    #pragma unroll
    for (int ch = 0; ch < 8; ++ch)
        #pragma unroll
        for (int r = 0; r < 16; ++r) o[ch][r] *= cr[r];

    __syncthreads();   // Lbuf visible; staging dead -> Obuf alias safe

    float* Obuf = (float*)smem;   // [64][260]
    if (kh == 1) {
        #pragma unroll
        for (int ch = 0; ch < 8; ++ch)
            #pragma unroll
            for (int r = 0; r < 16; ++r) {
                const int row = (r & 3) + 8 * (r >> 2) + 4 * hi;
                Obuf[(rg * 32 + row) * 260 + ch * 32 + ql] = o[ch][r];
            }
    }
    __syncthreads();

    if (kh == 0) {
        #pragma unroll
        for (int r = 0; r < 16; ++r) {
            const int row  = (r & 3) + 8 * (r >> 2) + 4 * hi;
            const int ridx = rg * 32 + row;
            const float inv = 1.0f / (Lbuf[ridx * 2] + Lbuf[ridx * 2 + 1]);
            #pragma unroll
            for (int ch = 0; ch < 8; ++ch)
                Out[(size_t)(gr0 + ridx) * D_ + ch * 32 + ql] =
                    (o[ch][r] + Obuf[ridx * 260 + ch * 32 + ql]) * inv;
        }
    }
}

extern "C" void kernel_launch(void* const* d_in, const int* in_sizes, int n_in,
                              void* d_out, int out_size, void* d_ws, size_t ws_size,
                              hipStream_t stream) {
    (void)out_size; (void)ws_size;
    const void *Xp = nullptr, *Wp = nullptr, *bp = nullptr;
    for (int i = 0; i < n_in; ++i) {
        if      (in_sizes[i] == B_ * S_ * D_) Xp = d_in[i];
        else if (in_sizes[i] == 3 * D_ * D_)  Wp = d_in[i];
        else if (in_sizes[i] == 3 * D_)       bp = d_in[i];
    }
    if (!Xp) Xp = d_in[0];
    if (!Wp) Wp = d_in[1];
    if (!bp) bp = d_in[2];

    float* Out = (float*)d_out;                                 // [B*S][256] f32

    unsigned short* Qb = (unsigned short*)d_ws;                 // 8 MiB
    unsigned short* Kb = Qb + (size_t)B_ * S_ * D_;             // 8 MiB
    unsigned short* Vt = Kb + (size_t)B_ * S_ * D_;             // 8 MiB
    // ws needed: 24 MiB

    dim3 pgrid(256, 12);
    qkv_proj<<<pgrid, 256, 0, stream>>>((const float*)Xp, (const float*)Wp,
                                        (const float*)bp, Qb, Kb, Vt);
    attn_fwd<<<256, 256, 0, stream>>>(Qb, Kb, Vt, Out);
}

// Round 13
// 197.240 us; speedup vs baseline: 2.5578x; 1.2270x over previous
//
#include <hip/hip_runtime.h>
#include <hip/hip_bf16.h>

#define B_ 4
#define S_ 4096
#define D_ 256

typedef __attribute__((ext_vector_type(8))) short bf16x8;
typedef __attribute__((ext_vector_type(4))) short short4v;
typedef __attribute__((ext_vector_type(4))) float f32x4;
typedef __attribute__((ext_vector_type(16))) float f32x16;

// round-to-nearest-even f32 -> bf16 bits (inputs finite)
static __device__ __forceinline__ unsigned short f2bf(float f) {
    unsigned int u = __float_as_uint(f);
    u += 0x7fffu + ((u >> 16) & 1u);
    return (unsigned short)(u >> 16);
}
static __device__ __forceinline__ float bf2f(unsigned short h) {
    return __uint_as_float(((unsigned int)h) << 16);
}

// async global -> LDS DMA, 16B per lane: LDS gets base + lane*16 (contiguous);
// global source is per-lane (pre-swizzled to realize swizzled LDS layouts).
static __device__ __forceinline__ void gload16(const void* g, void* l) {
    __builtin_amdgcn_global_load_lds(
        (const __attribute__((address_space(1))) unsigned int*)g,
        (__attribute__((address_space(3))) unsigned int*)l, 16, 0, 0);
}

// ---------------------------------------------------------------------------
// Kernel 1 (unchanged, certified): QKV = X @ W^T + b, f32 in, bf16 out.
// Q,K row-major [b*S+s][256]; V transposed Vt[b][d][s].
// ---------------------------------------------------------------------------
__global__ __launch_bounds__(256) void qkv_proj(
    const float* __restrict__ X, const float* __restrict__ W,
    const float* __restrict__ bias,
    unsigned short* __restrict__ Qb, unsigned short* __restrict__ Kb,
    unsigned short* __restrict__ Vt)
{
    __shared__ __align__(16) unsigned short As[64 * 64];
    __shared__ __align__(16) unsigned short Bs[64 * 64];

    const int tid  = threadIdx.x;
    const int lane = tid & 63;
    const int wid  = tid >> 6;
    const int wm   = wid >> 1, wn = wid & 1;
    const int c    = lane & 15, q4 = lane >> 4;
    const int gm0  = blockIdx.x * 64;
    const int gn0  = blockIdx.y * 64;
    const int sr   = tid >> 2;
    const int sc   = (tid & 3) * 16;

    f32x4 acc[2][2] = {};

    for (int kt = 0; kt < 4; ++kt) {
        const int k0 = kt * 64;
        {
            const float4* ga = (const float4*)(X + (size_t)(gm0 + sr) * D_ + k0 + sc);
            const float4* gb = (const float4*)(W + (size_t)(gn0 + sr) * D_ + k0 + sc);
            float4 a0 = ga[0], a1 = ga[1], a2 = ga[2], a3 = ga[3];
            float4 b0 = gb[0], b1 = gb[1], b2 = gb[2], b3 = gb[3];
            float af[16] = {a0.x,a0.y,a0.z,a0.w, a1.x,a1.y,a1.z,a1.w,
                            a2.x,a2.y,a2.z,a2.w, a3.x,a3.y,a3.z,a3.w};
            float bf[16] = {b0.x,b0.y,b0.z,b0.w, b1.x,b1.y,b1.z,b1.w,
                            b2.x,b2.y,b2.z,b2.w, b3.x,b3.y,b3.z,b3.w};
            bf16x8 av0, av1, bv0, bv1;
            #pragma unroll
            for (int j = 0; j < 8; ++j) {
                av0[j] = (short)f2bf(af[j]);     av1[j] = (short)f2bf(af[8 + j]);
                bv0[j] = (short)f2bf(bf[j]);     bv1[j] = (short)f2bf(bf[8 + j]);
            }
            const int sw = (sr & 7) << 3;
            *(bf16x8*)&As[sr * 64 + ((sc + 0) ^ sw)] = av0;
            *(bf16x8*)&As[sr * 64 + ((sc + 8) ^ sw)] = av1;
            *(bf16x8*)&Bs[sr * 64 + ((sc + 0) ^ sw)] = bv0;
            *(bf16x8*)&Bs[sr * 64 + ((sc + 8) ^ sw)] = bv1;
        }
        __syncthreads();
        const int sw = (c & 7) << 3;
        #pragma unroll
        for (int kk = 0; kk < 64; kk += 32) {
            bf16x8 afr[2], bfr[2];
            #pragma unroll
            for (int mf = 0; mf < 2; ++mf) {
                const int row = wm * 32 + mf * 16 + c;
                afr[mf] = *(const bf16x8*)&As[row * 64 + ((kk + 8 * q4) ^ sw)];
            }
            #pragma unroll
            for (int nf = 0; nf < 2; ++nf) {
                const int row = wn * 32 + nf * 16 + c;
                bfr[nf] = *(const bf16x8*)&Bs[row * 64 + ((kk + 8 * q4) ^ sw)];
            }
            #pragma unroll
            for (int mf = 0; mf < 2; ++mf)
                #pragma unroll
                for (int nf = 0; nf < 2; ++nf)
                    acc[mf][nf] = __builtin_amdgcn_mfma_f32_16x16x32_bf16(
                        afr[mf], bfr[nf], acc[mf][nf], 0, 0, 0);
        }
        __syncthreads();
    }

    const int b  = gm0 >> 12;
    const int s0 = gm0 & 4095;
    #pragma unroll
    for (int mf = 0; mf < 2; ++mf) {
        #pragma unroll
        for (int nf = 0; nf < 2; ++nf) {
            const int e  = gn0 + wn * 32 + nf * 16 + c;
            const float bv = bias[e];
            const int srow0 = s0 + wm * 32 + mf * 16 + 4 * q4;
            if (e < 256) {
                #pragma unroll
                for (int i = 0; i < 4; ++i)
                    Qb[((size_t)b * S_ + srow0 + i) * D_ + e] =
                        f2bf(acc[mf][nf][i] + bv);
            } else if (e < 512) {
                #pragma unroll
                for (int i = 0; i < 4; ++i)
                    Kb[((size_t)b * S_ + srow0 + i) * D_ + (e - 256)] =
                        f2bf(acc[mf][nf][i] + bv);
            } else {
                short4v pv;
                #pragma unroll
                for (int i = 0; i < 4; ++i)
                    pv[i] = (short)f2bf(acc[mf][nf][i] + bv);
                *(short4v*)&Vt[((size_t)(b * D_ + (e - 512))) * S_ + srow0] = pv;
            }
        }
    }
}

// ---------------------------------------------------------------------------
// Kernel 2: flash attention, 32x32x16 MFMA, swapped QK^T, in-register
// softmax (certified r12 math), with global_load_lds DMA staging.
// Block = 256 thr = 4 waves = 2 row-groups(32 rows) x 2 key-halves; 64 rows.
// LDS per buffer (64KB): K_h0[32][512B] slot^=(row&31) | K_h1 | V_h0[256][64B]
// slot^=((d>>1)&3) | V_h1.  Double-buffered (128KB) + M/L merge bufs.
// Staging: wave w DMAs 16 x 1KB chunks of {K_h0,K_h1,V_h0,V_h1}[w] into
// buffer p^1 (pre-swizzled per-lane source, linear LDS dest); the per-step
// barrier's implicit vmcnt(0) drain guarantees completion.
// ---------------------------------------------------------------------------
__global__ __launch_bounds__(256, 1) void attn_fwd(
    const unsigned short* __restrict__ Qb, const unsigned short* __restrict__ Kb,
    const unsigned short* __restrict__ Vt, float* __restrict__ Out)
{
    __shared__ __align__(16) char smem[132096];
    // [0,131072): 2 x 65536 buffers; [131072): Mbuf f32[64][2]; [131584): Lbuf

    const int bid  = blockIdx.x;
    const int xcd  = bid & 7;
    const int tile = (xcd >> 1) * 64 + (bid >> 3) * 2 + (xcd & 1); // [0,256)
    const int gr0  = tile * 64;
    const int b    = gr0 >> 12;

    const int tid  = threadIdx.x;
    const int wid  = tid >> 6, lane = tid & 63;
    const int ql   = lane & 31, hi = lane >> 5;
    const int rg   = wid & 1;             // row group (32 rows)
    const int kh   = wid >> 1;            // key half (compute role)
    const float C  = 0.09016844005556021f;   // log2(e)/sqrt(256)
    const float THR = 40.0f;              // defer-max threshold (raw score)

    // Q fragments (B operand): q = gr0 + rg*32 + ql; per mfma m: d = m*16+8*hi+j
    bf16x8 qf[16];
    {
        const size_t qrow = (size_t)(gr0 + rg * 32 + ql) * D_ + 8 * hi;
        #pragma unroll
        for (int m = 0; m < 16; ++m)
            qf[m] = *(const bf16x8*)&Qb[qrow + m * 16];
    }

    const unsigned short* Kbb = Kb + (size_t)b * S_ * D_;
    const unsigned short* Vtb = Vt + (size_t)b * D_ * S_;

    // --- DMA staging bases (role by wid; independent of compute role) ---
    // wid 0/1: K half wid. Chunk j = rows 2j,2j+1. Lane i: row=2j+(i>>5),
    //   stored slot (i&31) <- data slot (i&31)^row  (5-bit involution).
    // wid 2/3: V half wid-2. Chunk j = d rows 16j..16j+15. Lane i:
    //   d=16j+(i>>2), stored slot (i&3) <- data slot (i&3)^((i>>3)&3).
    const int kb_ = lane >> 5, i5 = lane & 31;
    const unsigned short* kdma = Kbb + (size_t)(wid * 2048 + kb_) * 256; // wid<2
    const int vh = wid - 2;
    const unsigned short* vdma = Vtb + (size_t)(lane >> 2) * S_ + vh * 2048
                               + (((lane & 3) ^ ((lane >> 3) & 3)) << 3); // wid>=2

    float* Mbuf = (float*)(smem + 131072);
    float* Lbuf = (float*)(smem + 131584);

    f32x16 o[8] = {};
    float m0 = -1.0e30f, l0 = 0.0f;

    // --- prologue: DMA tile 0 into buffer 0 ---
    if (wid < 2) {
        char* dst = smem + wid * 16384;
        #pragma unroll
        for (int j = 0; j < 16; ++j)
            gload16(kdma + j * 512 + ((i5 ^ ((2 * j + kb_) & 31)) << 3),
                    dst + j * 1024);
    } else {
        char* dst = smem + 32768 + vh * 16384;
        #pragma unroll
        for (int j = 0; j < 16; ++j)
            gload16(vdma + (size_t)j * 16 * S_, dst + j * 1024);
    }
    __builtin_amdgcn_s_waitcnt(0);
    __syncthreads();

    const int NS = 64;
    int p = 0;

    for (int s = 0; s < NS; ++s) {
        const char* Ksb = smem + p * 65536 + kh * 16384;
        const char* Vsb = smem + p * 65536 + 32768 + kh * 16384;

        // ---- QK^T (swapped), 2 accumulator chains ----
        f32x16 sa = {}, sb = {};
        #pragma unroll
        for (int m = 0; m < 8; ++m) {
            bf16x8 kf = *(const bf16x8*)(Ksb + ql * 512 + ((m * 32 + hi * 16) ^ (ql << 4)));
            sa = __builtin_amdgcn_mfma_f32_32x32x16_bf16(kf, qf[m], sa, 0, 0, 0);
        }
        #pragma unroll
        for (int m = 8; m < 16; ++m) {
            bf16x8 kf = *(const bf16x8*)(Ksb + ql * 512 + ((m * 32 + hi * 16) ^ (ql << 4)));
            sb = __builtin_amdgcn_mfma_f32_32x32x16_bf16(kf, qf[m], sb, 0, 0, 0);
        }
        f32x16 sacc;
        #pragma unroll
        for (int r = 0; r < 16; ++r) sacc[r] = sa[r] + sb[r];

        // ---- issue DMA for next tile into buffer p^1 (T14: after QK) ----
        if (s + 1 < NS) {
            const int kvn = (s + 1) * 32;
            if (wid < 2) {
                char* dst = smem + (p ^ 1) * 65536 + wid * 16384;
                const unsigned short* src0 = kdma + (size_t)kvn * 256;
                #pragma unroll
                for (int j = 0; j < 16; ++j)
                    gload16(src0 + j * 512 + ((i5 ^ ((2 * j + kb_) & 31)) << 3),
                            dst + j * 1024);
            } else {
                char* dst = smem + (p ^ 1) * 65536 + 32768 + vh * 16384;
                const unsigned short* src0 = vdma + kvn;
                #pragma unroll
                for (int j = 0; j < 16; ++j)
                    gload16(src0 + (size_t)j * 16 * S_, dst + j * 1024);
            }
        }

        // ---- row max: tree over 16 + 1 cross-hi ----
        float t[8];
        #pragma unroll
        for (int r = 0; r < 8; ++r) t[r] = fmaxf(sacc[r], sacc[r + 8]);
        #pragma unroll
        for (int r = 0; r < 4; ++r) t[r] = fmaxf(t[r], t[r + 4]);
        float rmax = fmaxf(fmaxf(t[0], t[1]), fmaxf(t[2], t[3]));
        rmax = fmaxf(rmax, __shfl_xor(rmax, 32));

        if (__any(rmax > m0 + THR)) {
            const float mn = fmaxf(m0, rmax);
            const float corr = exp2f((m0 - mn) * C);
            m0 = mn;
            l0 *= corr;
            #pragma unroll
            for (int r = 0; r < 16; ++r) {
                const int row = (r & 3) + 8 * (r >> 2) + 4 * hi;
                const float cr = __shfl(corr, row);
                #pragma unroll
                for (int ch = 0; ch < 8; ++ch) o[ch][r] *= cr;
            }
        }

        // ---- P = exp(S - m0), pack bf16 pairs ----
        float rsum = 0.f;
        unsigned int pk[8];
        #pragma unroll
        for (int tt = 0; tt < 8; ++tt) {
            const unsigned short u0 = f2bf(exp2f((sacc[2 * tt]     - m0) * C));
            const unsigned short u1 = f2bf(exp2f((sacc[2 * tt + 1] - m0) * C));
            rsum += bf2f(u0) + bf2f(u1);
            pk[tt] = (unsigned int)u0 | ((unsigned int)u1 << 16);
        }
        rsum += __shfl_xor(rsum, 32);
        l0 += rsum;

        unsigned int Ap[8];
        #pragma unroll
        for (int tt = 0; tt < 8; ++tt) Ap[tt] = __shfl_xor(pk[tt], 32);

        union U { unsigned int w[4]; bf16x8 v; };
        U pa0, pa1;
        if (hi == 0) {
            pa0.w[0] = pk[0]; pa0.w[1] = pk[1]; pa0.w[2] = Ap[0]; pa0.w[3] = Ap[1];
            pa1.w[0] = pk[4]; pa1.w[1] = pk[5]; pa1.w[2] = Ap[4]; pa1.w[3] = Ap[5];
        } else {
            pa0.w[0] = Ap[2]; pa0.w[1] = Ap[3]; pa0.w[2] = pk[2]; pa0.w[3] = pk[3];
            pa1.w[0] = Ap[6]; pa1.w[1] = Ap[7]; pa1.w[2] = pk[6]; pa1.w[3] = pk[7];
        }

        // ---- O += P @ V : V [256][64B], slot ^= ((d>>1)&3) ----
        const int vsw = ((ql >> 1) & 3) << 4;
        #pragma unroll
        for (int ch = 0; ch < 8; ++ch) {
            const char* vrow = Vsb + (ch * 32 + ql) * 64;
            bf16x8 vf0 = *(const bf16x8*)(vrow + ((hi * 16)      ^ vsw));
            bf16x8 vf1 = *(const bf16x8*)(vrow + ((hi * 16 + 32) ^ vsw));
            o[ch] = __builtin_amdgcn_mfma_f32_32x32x16_bf16(pa0.v, vf0, o[ch], 0, 0, 0);
            o[ch] = __builtin_amdgcn_mfma_f32_32x32x16_bf16(pa1.v, vf1, o[ch], 0, 0, 0);
        }

        __syncthreads();   // implicit vmcnt(0): next-tile DMAs complete
        p ^= 1;
    }

    // ---- merge across key halves (certified r12 logic) ----
    const int qidx = rg * 32 + ql;
    if (hi == 0) Mbuf[qidx * 2 + kh] = m0;
    __syncthreads();

    {
        const float gm = fmaxf(Mbuf[qidx * 2], Mbuf[qidx * 2 + 1]);
        l0 *= exp2f((m0 - gm) * C);
    }
    if (hi == 0) Lbuf[qidx * 2 + kh] = l0;

    float cr[16];
    #pragma unroll
    for (int r = 0; r < 16; ++r) {
        const int row  = (r & 3) + 8 * (r >> 2) + 4 * hi;
        const int ridx = rg * 32 + row;
        const float mw  = Mbuf[ridx * 2 + kh];
        const float gmr = fmaxf(Mbuf[ridx * 2], Mbuf[ridx * 2 + 1]);
        cr[r] = exp2f((mw - gmr) * C);
    }
    #pragma unroll
    for (int ch = 0; ch < 8; ++ch)
        #pragma unroll
        for (int r = 0; r < 16; ++r) o[ch][r] *= cr[r];

    __syncthreads();   // Lbuf visible; staging dead -> Obuf alias safe

    float* Obuf = (float*)smem;   // [64][260]
    if (kh == 1) {
        #pragma unroll
        for (int ch = 0; ch < 8; ++ch)
            #pragma unroll
            for (int r = 0; r < 16; ++r) {
                const int row = (r & 3) + 8 * (r >> 2) + 4 * hi;
                Obuf[(rg * 32 + row) * 260 + ch * 32 + ql] = o[ch][r];
            }
    }
    __syncthreads();

    if (kh == 0) {
        #pragma unroll
        for (int r = 0; r < 16; ++r) {
            const int row  = (r & 3) + 8 * (r >> 2) + 4 * hi;
            const int ridx = rg * 32 + row;
            const float inv = 1.0f / (Lbuf[ridx * 2] + Lbuf[ridx * 2 + 1]);
            #pragma unroll
            for (int ch = 0; ch < 8; ++ch)
                Out[(size_t)(gr0 + ridx) * D_ + ch * 32 + ql] =
                    (o[ch][r] + Obuf[ridx * 260 + ch * 32 + ql]) * inv;
        }
    }
}

extern "C" void kernel_launch(void* const* d_in, const int* in_sizes, int n_in,
                              void* d_out, int out_size, void* d_ws, size_t ws_size,
                              hipStream_t stream) {
    (void)out_size; (void)ws_size;
    const void *Xp = nullptr, *Wp = nullptr, *bp = nullptr;
    for (int i = 0; i < n_in; ++i) {
        if      (in_sizes[i] == B_ * S_ * D_) Xp = d_in[i];
        else if (in_sizes[i] == 3 * D_ * D_)  Wp = d_in[i];
        else if (in_sizes[i] == 3 * D_)       bp = d_in[i];
    }
    if (!Xp) Xp = d_in[0];
    if (!Wp) Wp = d_in[1];
    if (!bp) bp = d_in[2];

    float* Out = (float*)d_out;                                 // [B*S][256] f32

    unsigned short* Qb = (unsigned short*)d_ws;                 // 8 MiB
    unsigned short* Kb = Qb + (size_t)B_ * S_ * D_;             // 8 MiB
    unsigned short* Vt = Kb + (size_t)B_ * S_ * D_;             // 8 MiB
    // ws needed: 24 MiB

    dim3 pgrid(256, 12);
    qkv_proj<<<pgrid, 256, 0, stream>>>((const float*)Xp, (const float*)Wp,
                                        (const float*)bp, Qb, Kb, Vt);
    attn_fwd<<<256, 256, 0, stream>>>(Qb, Kb, Vt, Out);
}

// Round 14
// 161.839 us; speedup vs baseline: 3.1173x; 1.2187x over previous
//
#include <hip/hip_runtime.h>
#include <hip/hip_bf16.h>

#define B_ 4
#define S_ 4096
#define D_ 256

typedef __attribute__((ext_vector_type(8))) short bf16x8;
typedef __attribute__((ext_vector_type(4))) short short4v;
typedef __attribute__((ext_vector_type(4))) float f32x4;

// round-to-nearest-even f32 -> bf16 bits (inputs finite)
static __device__ __forceinline__ unsigned short f2bf(float f) {
    unsigned int u = __float_as_uint(f);
    u += 0x7fffu + ((u >> 16) & 1u);
    return (unsigned short)(u >> 16);
}
static __device__ __forceinline__ float bf2f(unsigned short h) {
    return __uint_as_float(((unsigned int)h) << 16);
}
// packed f32x2 -> bf16x2 (RNE), single HW op (T12)
static __device__ __forceinline__ unsigned int cvtpk(float lo, float hi) {
    unsigned int r;
    asm("v_cvt_pk_bf16_f32 %0, %1, %2" : "=v"(r) : "v"(lo), "v"(hi));
    return r;
}

// async global -> LDS DMA, 16B/lane: LDS gets base + lane*16 (linear);
// global source is per-lane (pre-swizzled to realize swizzled LDS layouts).
static __device__ __forceinline__ void gload16(const void* g, void* l) {
    __builtin_amdgcn_global_load_lds(
        (const __attribute__((address_space(1))) unsigned int*)g,
        (__attribute__((address_space(3))) unsigned int*)l, 16, 0, 0);
}

// ---------------------------------------------------------------------------
// Kernel 1 (unchanged, certified): QKV = X @ W^T + b, f32 in, bf16 out.
// Q,K row-major [b*S+s][256]; V transposed Vt[b][d][s].
// ---------------------------------------------------------------------------
__global__ __launch_bounds__(256) void qkv_proj(
    const float* __restrict__ X, const float* __restrict__ W,
    const float* __restrict__ bias,
    unsigned short* __restrict__ Qb, unsigned short* __restrict__ Kb,
    unsigned short* __restrict__ Vt)
{
    __shared__ __align__(16) unsigned short As[64 * 64];
    __shared__ __align__(16) unsigned short Bs[64 * 64];

    const int tid  = threadIdx.x;
    const int lane = tid & 63;
    const int wid  = tid >> 6;
    const int wm   = wid >> 1, wn = wid & 1;
    const int c    = lane & 15, q4 = lane >> 4;
    const int gm0  = blockIdx.x * 64;
    const int gn0  = blockIdx.y * 64;
    const int sr   = tid >> 2;
    const int sc   = (tid & 3) * 16;

    f32x4 acc[2][2] = {};

    for (int kt = 0; kt < 4; ++kt) {
        const int k0 = kt * 64;
        {
            const float4* ga = (const float4*)(X + (size_t)(gm0 + sr) * D_ + k0 + sc);
            const float4* gb = (const float4*)(W + (size_t)(gn0 + sr) * D_ + k0 + sc);
            float4 a0 = ga[0], a1 = ga[1], a2 = ga[2], a3 = ga[3];
            float4 b0 = gb[0], b1 = gb[1], b2 = gb[2], b3 = gb[3];
            float af[16] = {a0.x,a0.y,a0.z,a0.w, a1.x,a1.y,a1.z,a1.w,
                            a2.x,a2.y,a2.z,a2.w, a3.x,a3.y,a3.z,a3.w};
            float bf[16] = {b0.x,b0.y,b0.z,b0.w, b1.x,b1.y,b1.z,b1.w,
                            b2.x,b2.y,b2.z,b2.w, b3.x,b3.y,b3.z,b3.w};
            bf16x8 av0, av1, bv0, bv1;
            #pragma unroll
            for (int j = 0; j < 8; ++j) {
                av0[j] = (short)f2bf(af[j]);     av1[j] = (short)f2bf(af[8 + j]);
                bv0[j] = (short)f2bf(bf[j]);     bv1[j] = (short)f2bf(bf[8 + j]);
            }
            const int sw = (sr & 7) << 3;
            *(bf16x8*)&As[sr * 64 + ((sc + 0) ^ sw)] = av0;
            *(bf16x8*)&As[sr * 64 + ((sc + 8) ^ sw)] = av1;
            *(bf16x8*)&Bs[sr * 64 + ((sc + 0) ^ sw)] = bv0;
            *(bf16x8*)&Bs[sr * 64 + ((sc + 8) ^ sw)] = bv1;
        }
        __syncthreads();
        const int sw = (c & 7) << 3;
        #pragma unroll
        for (int kk = 0; kk < 64; kk += 32) {
            bf16x8 afr[2], bfr[2];
            #pragma unroll
            for (int mf = 0; mf < 2; ++mf) {
                const int row = wm * 32 + mf * 16 + c;
                afr[mf] = *(const bf16x8*)&As[row * 64 + ((kk + 8 * q4) ^ sw)];
            }
            #pragma unroll
            for (int nf = 0; nf < 2; ++nf) {
                const int row = wn * 32 + nf * 16 + c;
                bfr[nf] = *(const bf16x8*)&Bs[row * 64 + ((kk + 8 * q4) ^ sw)];
            }
            #pragma unroll
            for (int mf = 0; mf < 2; ++mf)
                #pragma unroll
                for (int nf = 0; nf < 2; ++nf)
                    acc[mf][nf] = __builtin_amdgcn_mfma_f32_16x16x32_bf16(
                        afr[mf], bfr[nf], acc[mf][nf], 0, 0, 0);
        }
        __syncthreads();
    }

    const int b  = gm0 >> 12;
    const int s0 = gm0 & 4095;
    #pragma unroll
    for (int mf = 0; mf < 2; ++mf) {
        #pragma unroll
        for (int nf = 0; nf < 2; ++nf) {
            const int e  = gn0 + wn * 32 + nf * 16 + c;
            const float bv = bias[e];
            const int srow0 = s0 + wm * 32 + mf * 16 + 4 * q4;
            if (e < 256) {
                #pragma unroll
                for (int i = 0; i < 4; ++i)
                    Qb[((size_t)b * S_ + srow0 + i) * D_ + e] =
                        f2bf(acc[mf][nf][i] + bv);
            } else if (e < 512) {
                #pragma unroll
                for (int i = 0; i < 4; ++i)
                    Kb[((size_t)b * S_ + srow0 + i) * D_ + (e - 256)] =
                        f2bf(acc[mf][nf][i] + bv);
            } else {
                short4v pv;
                #pragma unroll
                for (int i = 0; i < 4; ++i)
                    pv[i] = (short)f2bf(acc[mf][nf][i] + bv);
                *(short4v*)&Vt[((size_t)(b * D_ + (e - 512))) * S_ + srow0] = pv;
            }
        }
    }
}

// ---------------------------------------------------------------------------
// Kernel 2: flash attention, 512 threads = 8 waves = 4 row-groups(16 q) x
// 2 key-halves -> 8 waves/CU = 2 waves/SIMD (single-block co-residency,
// proven r10). 16x16x32 MFMAs:
//   QK swapped:  sacc[kc] = mfma(Kfrag, Qfrag): lane(qi=l&15, g=l>>4) holds
//                scores of ITS q for keys kc*16 + 4g + r.
//   PV swapped:  o[dc] = mfma(Vt-frag, P^T-frag): D[d-local][q] -> lane's o
//                all belong to q=qi; d = dc*16 + 4g + r.  Softmax state
//                (m,l,corr) is a per-lane scalar.
// P^T B-frag assembly: 4 cvt_pk packs + 8 shfl + 4 selects (in-register).
// DMA staging (global_load_lds), double-buffered 2x64KB, same swizzles as
// r13 re-derived for 16-row waves; DMA issued at step TOP.
// LDS: [0,131072) 2 x {K_h0 16K|K_h1 16K|V_h0 16K|V_h1 16K};
//      Mbuf/Lbuf at 131072/131584; Obuf f32[64][260] aliases [0,66560).
// ---------------------------------------------------------------------------
__global__ __launch_bounds__(512, 2) void attn_fwd(
    const unsigned short* __restrict__ Qb, const unsigned short* __restrict__ Kb,
    const unsigned short* __restrict__ Vt, float* __restrict__ Out)
{
    __shared__ __align__(16) char smem[132096];

    const int bid  = blockIdx.x;
    const int xcd  = bid & 7;
    const int tile = (xcd >> 1) * 64 + (bid >> 3) * 2 + (xcd & 1); // [0,256)
    const int gr0  = tile * 64;
    const int b    = gr0 >> 12;

    const int tid  = threadIdx.x;
    const int wid  = tid >> 6, lane = tid & 63;
    const int qi   = lane & 15, g = lane >> 4;
    const int rg   = wid & 3;             // row group (16 rows)
    const int kh   = wid >> 2;            // key half (compute role)
    const int q0   = gr0 + rg * 16;
    const float C  = 0.09016844005556021f;   // log2(e)/sqrt(256)
    const float THR = 40.0f;

    // Q fragments (B operand): lane col = qi; d = m*32 + 8g + j
    bf16x8 qf[8];
    {
        const size_t qrow = (size_t)(q0 + qi) * D_ + 8 * g;
        #pragma unroll
        for (int m = 0; m < 8; ++m)
            qf[m] = *(const bf16x8*)&Qb[qrow + m * 32];
    }

    const unsigned short* Kbb = Kb + (size_t)b * S_ * D_;
    const unsigned short* Vtb = Vt + (size_t)b * D_ * S_;

    // --- DMA staging roles (8 gload16/thread): waves 0-3 K, 4-7 V ---
    const int isK = (wid < 4);
    const int sth = (wid >> 1) & 1;       // staged key half
    const int sub = wid & 1;              // sub-range within half
    int soff[8];                          // per-lane element offsets (step-inv)
    int doff[8];                          // LDS byte offsets within buffer
    if (isK) {
        const int l5 = lane >> 5, i5 = lane & 31;
        #pragma unroll
        for (int j = 0; j < 8; ++j) {
            const int r0 = sub * 16 + 2 * j + l5;       // tile row 0..31
            soff[j] = (sth * 2048 + r0) * 256 + ((i5 ^ r0) << 3);
            doff[j] = sth * 16384 + (sub * 16 + 2 * j) * 512;
        }
    } else {
        #pragma unroll
        for (int j = 0; j < 8; ++j) {
            const int d = sub * 128 + 16 * j + (lane >> 2);
            soff[j] = d * S_ + sth * 2048 + ((((lane & 3) ^ ((lane >> 3) & 3))) << 3);
            doff[j] = 32768 + sth * 16384 + (sub * 128 + 16 * j) * 64;
        }
    }
    const unsigned short* sbase = isK ? Kbb : Vtb;

    float* Mbuf = (float*)(smem + 131072);
    float* Lbuf = (float*)(smem + 131584);

    f32x4 o[16] = {};
    float m0 = -1.0e30f, l0 = 0.0f;

    // --- prologue: DMA tile 0 into buffer 0 ---
    #pragma unroll
    for (int j = 0; j < 8; ++j)
        gload16(sbase + soff[j], smem + doff[j]);
    __builtin_amdgcn_s_waitcnt(0);
    __syncthreads();

    const int NS = 64;
    int p = 0;
    const int vsw = (g ^ ((qi >> 1) & 3)) << 4;   // V read swizzle (lane-const)

    for (int s = 0; s < NS; ++s) {
        // ---- issue DMA for tile s+1 into buffer p^1 (step top: max slack) ----
        if (s + 1 < NS) {
            const unsigned short* sb = sbase + (isK ? (s + 1) * 32 * 256
                                                    : (s + 1) * 32);
            const int bufo = (p ^ 1) * 65536;
            #pragma unroll
            for (int j = 0; j < 8; ++j)
                gload16(sb + soff[j], smem + bufo + doff[j]);
        }

        const char* Ksb = smem + p * 65536 + kh * 16384;
        const char* Vsb = smem + p * 65536 + 32768 + kh * 16384;

        // ---- QK^T (swapped), 2 independent chains ----
        f32x4 sacc[2] = {};
        #pragma unroll
        for (int kc = 0; kc < 2; ++kc) {
            const int kr = kc * 16 + qi;
            const char* krow = Ksb + kr * 512;
            #pragma unroll
            for (int m = 0; m < 8; ++m) {
                bf16x8 kf = *(const bf16x8*)(krow + (((4 * m + g) ^ kr) << 4));
                sacc[kc] = __builtin_amdgcn_mfma_f32_16x16x32_bf16(
                    kf, qf[m], sacc[kc], 0, 0, 0);
            }
        }

        // ---- per-lane softmax (q = qi): 8 local + 2 cross-group shfl ----
        float rmax = fmaxf(fmaxf(fmaxf(sacc[0][0], sacc[0][1]),
                                 fmaxf(sacc[0][2], sacc[0][3])),
                           fmaxf(fmaxf(sacc[1][0], sacc[1][1]),
                                 fmaxf(sacc[1][2], sacc[1][3])));
        rmax = fmaxf(rmax, __shfl_xor(rmax, 16));
        rmax = fmaxf(rmax, __shfl_xor(rmax, 32));

        if (__any(rmax > m0 + THR)) {
            const float mn = fmaxf(m0, rmax);
            const float corr = exp2f((m0 - mn) * C);
            m0 = mn;
            l0 *= corr;
            #pragma unroll
            for (int dc = 0; dc < 16; ++dc)
                #pragma unroll
                for (int r = 0; r < 4; ++r) o[dc][r] *= corr;
        }

        float p8[2][4];
        float rsum = 0.f;
        #pragma unroll
        for (int kc = 0; kc < 2; ++kc)
            #pragma unroll
            for (int r = 0; r < 4; ++r) {
                p8[kc][r] = exp2f((sacc[kc][r] - m0) * C);
                rsum += p8[kc][r];
            }
        rsum += __shfl_xor(rsum, 16);
        rsum += __shfl_xor(rsum, 32);
        l0 += rsum;

        // ---- pack P to bf16 pairs (HW cvt_pk) ----
        unsigned int pk0[2], pk1[2];
        pk0[0] = cvtpk(p8[0][0], p8[0][1]);  pk0[1] = cvtpk(p8[0][2], p8[0][3]);
        pk1[0] = cvtpk(p8[1][0], p8[1][1]);  pk1[1] = cvtpk(p8[1][2], p8[1][3]);

        // ---- assemble P^T B-fragment: k = 8g + j for own q ----
        const int A0 = qi + ((g & 1) << 5);   // src lane: group (g&1)*2
        const int A1 = A0 + 16;
        const unsigned int s00 = __shfl(pk0[0], A0), s01 = __shfl(pk0[1], A0);
        const unsigned int s02 = __shfl(pk0[0], A1), s03 = __shfl(pk0[1], A1);
        const unsigned int s10 = __shfl(pk1[0], A0), s11 = __shfl(pk1[1], A0);
        const unsigned int s12 = __shfl(pk1[0], A1), s13 = __shfl(pk1[1], A1);
        const bool hk = (g >> 1);             // which kc this lane needs
        union U { unsigned int w[4]; bf16x8 v; } pa;
        pa.w[0] = hk ? s10 : s00;  pa.w[1] = hk ? s11 : s01;
        pa.w[2] = hk ? s12 : s02;  pa.w[3] = hk ? s13 : s03;

        // ---- O^T += Vt-frag x P^T : 16 d-chunks ----
        #pragma unroll
        for (int dc = 0; dc < 16; ++dc) {
            bf16x8 vf = *(const bf16x8*)(Vsb + (dc * 16 + qi) * 64 + vsw);
            o[dc] = __builtin_amdgcn_mfma_f32_16x16x32_bf16(vf, pa.v, o[dc], 0, 0, 0);
        }

        __syncthreads();   // implicit vmcnt(0): tile s+1 DMAs complete
        p ^= 1;
    }

    // ---- merge across key halves (per-lane scalar state) ----
    const int qidx = rg * 16 + qi;            // block-local row
    if (g == 0) Mbuf[qidx * 2 + kh] = m0;
    __syncthreads();

    {
        const float gm = fmaxf(Mbuf[qidx * 2], Mbuf[qidx * 2 + 1]);
        const float corr = exp2f((m0 - gm) * C);
        l0 *= corr;
        #pragma unroll
        for (int dc = 0; dc < 16; ++dc)
            #pragma unroll
            for (int r = 0; r < 4; ++r) o[dc][r] *= corr;
    }
    if (g == 0) Lbuf[qidx * 2 + kh] = l0;

    float* Obuf = (float*)smem;               // [64][260], aliases KV buffers
    if (kh == 1) {
        #pragma unroll
        for (int dc = 0; dc < 16; ++dc)
            #pragma unroll
            for (int r = 0; r < 4; ++r)
                Obuf[qidx * 260 + dc * 16 + 4 * g + r] = o[dc][r];
    }
    __syncthreads();

    if (kh == 0) {
        const float inv = 1.0f / (Lbuf[qidx * 2] + Lbuf[qidx * 2 + 1]);
        #pragma unroll
        for (int dc = 0; dc < 16; ++dc)
            #pragma unroll
            for (int r = 0; r < 4; ++r) {
                const int d = dc * 16 + 4 * g + r;
                Out[(size_t)(q0 + qi) * D_ + d] =
                    (o[dc][r] + Obuf[qidx * 260 + d]) * inv;
            }
    }
}

extern "C" void kernel_launch(void* const* d_in, const int* in_sizes, int n_in,
                              void* d_out, int out_size, void* d_ws, size_t ws_size,
                              hipStream_t stream) {
    (void)out_size; (void)ws_size;
    const void *Xp = nullptr, *Wp = nullptr, *bp = nullptr;
    for (int i = 0; i < n_in; ++i) {
        if      (in_sizes[i] == B_ * S_ * D_) Xp = d_in[i];
        else if (in_sizes[i] == 3 * D_ * D_)  Wp = d_in[i];
        else if (in_sizes[i] == 3 * D_)       bp = d_in[i];
    }
    if (!Xp) Xp = d_in[0];
    if (!Wp) Wp = d_in[1];
    if (!bp) bp = d_in[2];

    float* Out = (float*)d_out;                                 // [B*S][256] f32

    unsigned short* Qb = (unsigned short*)d_ws;                 // 8 MiB
    unsigned short* Kb = Qb + (size_t)B_ * S_ * D_;             // 8 MiB
    unsigned short* Vt = Kb + (size_t)B_ * S_ * D_;             // 8 MiB
    // ws needed: 24 MiB

    dim3 pgrid(256, 12);
    qkv_proj<<<pgrid, 256, 0, stream>>>((const float*)Xp, (const float*)Wp,
                                        (const float*)bp, Qb, Kb, Vt);
    attn_fwd<<<256, 512, 0, stream>>>(Qb, Kb, Vt, Out);
}

// Round 15
// 160.634 us; speedup vs baseline: 3.1407x; 1.0075x over previous
//
#include <hip/hip_runtime.h>
#include <hip/hip_bf16.h>

#define B_ 4
#define S_ 4096
#define D_ 256

typedef __attribute__((ext_vector_type(8))) short bf16x8;
typedef __attribute__((ext_vector_type(4))) short short4v;
typedef __attribute__((ext_vector_type(4))) float f32x4;

// round-to-nearest-even f32 -> bf16 bits (inputs finite)
static __device__ __forceinline__ unsigned short f2bf(float f) {
    unsigned int u = __float_as_uint(f);
    u += 0x7fffu + ((u >> 16) & 1u);
    return (unsigned short)(u >> 16);
}
static __device__ __forceinline__ float bf2f(unsigned short h) {
    return __uint_as_float(((unsigned int)h) << 16);
}
// packed f32x2 -> bf16x2 (RNE), single HW op (T12)
static __device__ __forceinline__ unsigned int cvtpk(float lo, float hi) {
    unsigned int r;
    asm("v_cvt_pk_bf16_f32 %0, %1, %2" : "=v"(r) : "v"(lo), "v"(hi));
    return r;
}

// async global -> LDS DMA, 16B/lane: LDS gets base + lane*16 (linear);
// global source is per-lane (pre-swizzled to realize swizzled LDS layouts).
static __device__ __forceinline__ void gload16(const void* g, void* l) {
    __builtin_amdgcn_global_load_lds(
        (const __attribute__((address_space(1))) unsigned int*)g,
        (__attribute__((address_space(3))) unsigned int*)l, 16, 0, 0);
}

// ---------------------------------------------------------------------------
// Kernel 1: QKV = X @ W^T + b, f32 in, bf16 out. BM=128, BN=128, BK=64.
// 4 waves (2x2), each 64x64 via 4x4 16x16x32 MFMAs. Same certified swizzle
// (elem idx ^ ((row&7)<<3)) and Q/K/Vt routing as rounds 6-14; tile doubled
// both ways to halve X and W L2/L3 traffic (m93 ladder step).
// Q,K row-major [b*S+s][256]; V transposed Vt[b][d][s].
// ---------------------------------------------------------------------------
__global__ __launch_bounds__(256) void qkv_proj(
    const float* __restrict__ X, const float* __restrict__ W,
    const float* __restrict__ bias,
    unsigned short* __restrict__ Qb, unsigned short* __restrict__ Kb,
    unsigned short* __restrict__ Vt)
{
    __shared__ __align__(16) unsigned short As[128 * 64];
    __shared__ __align__(16) unsigned short Bs[128 * 64];

    const int tid  = threadIdx.x;
    const int lane = tid & 63;
    const int wid  = tid >> 6;
    const int wm   = wid >> 1, wn = wid & 1;
    const int c    = lane & 15, q4 = lane >> 4;
    const int gm0  = blockIdx.x * 128;   // row tile in M = b*S+s
    const int gn0  = blockIdx.y * 128;   // col tile in E = 768
    const int sr   = tid >> 1;           // staging row 0..127
    const int sc   = (tid & 1) * 32;     // staging col {0,32}

    f32x4 acc[4][4] = {};

    for (int kt = 0; kt < 4; ++kt) {
        const int k0 = kt * 64;
        // ---- stage X and W tiles (f32 -> bf16, swizzled) ----
        {
            const float4* ga = (const float4*)(X + (size_t)(gm0 + sr) * D_ + k0 + sc);
            const float4* gb = (const float4*)(W + (size_t)(gn0 + sr) * D_ + k0 + sc);
            const int sw = (sr & 7) << 3;
            #pragma unroll
            for (int h = 0; h < 4; ++h) {
                float4 a0 = ga[2 * h], a1 = ga[2 * h + 1];
                float4 b0 = gb[2 * h], b1 = gb[2 * h + 1];
                float af[8] = {a0.x,a0.y,a0.z,a0.w, a1.x,a1.y,a1.z,a1.w};
                float bf[8] = {b0.x,b0.y,b0.z,b0.w, b1.x,b1.y,b1.z,b1.w};
                bf16x8 av, bv;
                #pragma unroll
                for (int j = 0; j < 8; ++j) {
                    av[j] = (short)f2bf(af[j]);
                    bv[j] = (short)f2bf(bf[j]);
                }
                *(bf16x8*)&As[sr * 64 + ((sc + h * 8) ^ sw)] = av;
                *(bf16x8*)&Bs[sr * 64 + ((sc + h * 8) ^ sw)] = bv;
            }
        }
        __syncthreads();
        // ---- MFMA over this K-slab ----
        const int sw = (c & 7) << 3;
        #pragma unroll
        for (int kk = 0; kk < 64; kk += 32) {
            bf16x8 afr[4], bfr[4];
            #pragma unroll
            for (int mf = 0; mf < 4; ++mf) {
                const int row = wm * 64 + mf * 16 + c;
                afr[mf] = *(const bf16x8*)&As[row * 64 + ((kk + 8 * q4) ^ sw)];
            }
            #pragma unroll
            for (int nf = 0; nf < 4; ++nf) {
                const int row = wn * 64 + nf * 16 + c;
                bfr[nf] = *(const bf16x8*)&Bs[row * 64 + ((kk + 8 * q4) ^ sw)];
            }
            #pragma unroll
            for (int mf = 0; mf < 4; ++mf)
                #pragma unroll
                for (int nf = 0; nf < 4; ++nf)
                    acc[mf][nf] = __builtin_amdgcn_mfma_f32_16x16x32_bf16(
                        afr[mf], bfr[nf], acc[mf][nf], 0, 0, 0);
        }
        __syncthreads();
    }

    // ---- epilogue: +bias, route to Q / K / Vt (certified logic) ----
    const int b  = gm0 >> 12;            // 128 | 4096 -> uniform per block
    const int s0 = gm0 & 4095;
    #pragma unroll
    for (int mf = 0; mf < 4; ++mf) {
        #pragma unroll
        for (int nf = 0; nf < 4; ++nf) {
            const int e  = gn0 + wn * 64 + nf * 16 + c;
            const float bv = bias[e];
            const int srow0 = s0 + wm * 64 + mf * 16 + 4 * q4;  // +i
            if (e < 256) {
                #pragma unroll
                for (int i = 0; i < 4; ++i)
                    Qb[((size_t)b * S_ + srow0 + i) * D_ + e] =
                        f2bf(acc[mf][nf][i] + bv);
            } else if (e < 512) {
                #pragma unroll
                for (int i = 0; i < 4; ++i)
                    Kb[((size_t)b * S_ + srow0 + i) * D_ + (e - 256)] =
                        f2bf(acc[mf][nf][i] + bv);
            } else {
                short4v pv;
                #pragma unroll
                for (int i = 0; i < 4; ++i)
                    pv[i] = (short)f2bf(acc[mf][nf][i] + bv);
                *(short4v*)&Vt[((size_t)(b * D_ + (e - 512))) * S_ + srow0] = pv;
            }
        }
    }
}

// ---------------------------------------------------------------------------
// Kernel 2: flash attention (byte-identical to round 14 except s_setprio
// around the QK and PV MFMA clusters — T5). 512 threads = 8 waves =
// 4 row-groups(16 q) x 2 key-halves -> 2 waves/SIMD.
// QK swapped: sacc[kc] = mfma(Kfrag, Qfrag); PV swapped:
// o[dc] = mfma(Vt-frag, P^T-frag) -> per-lane scalar softmax state.
// DMA staging (global_load_lds), double-buffered 2x64KB.
// ---------------------------------------------------------------------------
__global__ __launch_bounds__(512, 2) void attn_fwd(
    const unsigned short* __restrict__ Qb, const unsigned short* __restrict__ Kb,
    const unsigned short* __restrict__ Vt, float* __restrict__ Out)
{
    __shared__ __align__(16) char smem[132096];

    const int bid  = blockIdx.x;
    const int xcd  = bid & 7;
    const int tile = (xcd >> 1) * 64 + (bid >> 3) * 2 + (xcd & 1); // [0,256)
    const int gr0  = tile * 64;
    const int b    = gr0 >> 12;

    const int tid  = threadIdx.x;
    const int wid  = tid >> 6, lane = tid & 63;
    const int qi   = lane & 15, g = lane >> 4;
    const int rg   = wid & 3;             // row group (16 rows)
    const int kh   = wid >> 2;            // key half (compute role)
    const int q0   = gr0 + rg * 16;
    const float C  = 0.09016844005556021f;   // log2(e)/sqrt(256)
    const float THR = 40.0f;

    // Q fragments (B operand): lane col = qi; d = m*32 + 8g + j
    bf16x8 qf[8];
    {
        const size_t qrow = (size_t)(q0 + qi) * D_ + 8 * g;
        #pragma unroll
        for (int m = 0; m < 8; ++m)
            qf[m] = *(const bf16x8*)&Qb[qrow + m * 32];
    }

    const unsigned short* Kbb = Kb + (size_t)b * S_ * D_;
    const unsigned short* Vtb = Vt + (size_t)b * D_ * S_;

    // --- DMA staging roles (8 gload16/thread): waves 0-3 K, 4-7 V ---
    const int isK = (wid < 4);
    const int sth = (wid >> 1) & 1;       // staged key half
    const int sub = wid & 1;              // sub-range within half
    int soff[8];                          // per-lane element offsets (step-inv)
    int doff[8];                          // LDS byte offsets within buffer
    if (isK) {
        const int l5 = lane >> 5, i5 = lane & 31;
        #pragma unroll
        for (int j = 0; j < 8; ++j) {
            const int r0 = sub * 16 + 2 * j + l5;       // tile row 0..31
            soff[j] = (sth * 2048 + r0) * 256 + ((i5 ^ r0) << 3);
            doff[j] = sth * 16384 + (sub * 16 + 2 * j) * 512;
        }
    } else {
        #pragma unroll
        for (int j = 0; j < 8; ++j) {
            const int d = sub * 128 + 16 * j + (lane >> 2);
            soff[j] = d * S_ + sth * 2048 + ((((lane & 3) ^ ((lane >> 3) & 3))) << 3);
            doff[j] = 32768 + sth * 16384 + (sub * 128 + 16 * j) * 64;
        }
    }
    const unsigned short* sbase = isK ? Kbb : Vtb;

    float* Mbuf = (float*)(smem + 131072);
    float* Lbuf = (float*)(smem + 131584);

    f32x4 o[16] = {};
    float m0 = -1.0e30f, l0 = 0.0f;

    // --- prologue: DMA tile 0 into buffer 0 ---
    #pragma unroll
    for (int j = 0; j < 8; ++j)
        gload16(sbase + soff[j], smem + doff[j]);
    __builtin_amdgcn_s_waitcnt(0);
    __syncthreads();

    const int NS = 64;
    int p = 0;
    const int vsw = (g ^ ((qi >> 1) & 3)) << 4;   // V read swizzle (lane-const)

    for (int s = 0; s < NS; ++s) {
        // ---- issue DMA for tile s+1 into buffer p^1 (step top: max slack) ----
        if (s + 1 < NS) {
            const unsigned short* sb = sbase + (isK ? (s + 1) * 32 * 256
                                                    : (s + 1) * 32);
            const int bufo = (p ^ 1) * 65536;
            #pragma unroll
            for (int j = 0; j < 8; ++j)
                gload16(sb + soff[j], smem + bufo + doff[j]);
        }

        const char* Ksb = smem + p * 65536 + kh * 16384;
        const char* Vsb = smem + p * 65536 + 32768 + kh * 16384;

        // ---- QK^T (swapped), 2 independent chains (T5: setprio) ----
        f32x4 sacc[2] = {};
        __builtin_amdgcn_s_setprio(1);
        #pragma unroll
        for (int kc = 0; kc < 2; ++kc) {
            const int kr = kc * 16 + qi;
            const char* krow = Ksb + kr * 512;
            #pragma unroll
            for (int m = 0; m < 8; ++m) {
                bf16x8 kf = *(const bf16x8*)(krow + (((4 * m + g) ^ kr) << 4));
                sacc[kc] = __builtin_amdgcn_mfma_f32_16x16x32_bf16(
                    kf, qf[m], sacc[kc], 0, 0, 0);
            }
        }
        __builtin_amdgcn_s_setprio(0);

        // ---- per-lane softmax (q = qi): 8 local + 2 cross-group shfl ----
        float rmax = fmaxf(fmaxf(fmaxf(sacc[0][0], sacc[0][1]),
                                 fmaxf(sacc[0][2], sacc[0][3])),
                           fmaxf(fmaxf(sacc[1][0], sacc[1][1]),
                                 fmaxf(sacc[1][2], sacc[1][3])));
        rmax = fmaxf(rmax, __shfl_xor(rmax, 16));
        rmax = fmaxf(rmax, __shfl_xor(rmax, 32));

        if (__any(rmax > m0 + THR)) {
            const float mn = fmaxf(m0, rmax);
            const float corr = exp2f((m0 - mn) * C);
            m0 = mn;
            l0 *= corr;
            #pragma unroll
            for (int dc = 0; dc < 16; ++dc)
                #pragma unroll
                for (int r = 0; r < 4; ++r) o[dc][r] *= corr;
        }

        float p8[2][4];
        float rsum = 0.f;
        #pragma unroll
        for (int kc = 0; kc < 2; ++kc)
            #pragma unroll
            for (int r = 0; r < 4; ++r) {
                p8[kc][r] = exp2f((sacc[kc][r] - m0) * C);
                rsum += p8[kc][r];
            }
        rsum += __shfl_xor(rsum, 16);
        rsum += __shfl_xor(rsum, 32);
        l0 += rsum;

        // ---- pack P to bf16 pairs (HW cvt_pk) ----
        unsigned int pk0[2], pk1[2];
        pk0[0] = cvtpk(p8[0][0], p8[0][1]);  pk0[1] = cvtpk(p8[0][2], p8[0][3]);
        pk1[0] = cvtpk(p8[1][0], p8[1][1]);  pk1[1] = cvtpk(p8[1][2], p8[1][3]);

        // ---- assemble P^T B-fragment: k = 8g + j for own q ----
        const int A0 = qi + ((g & 1) << 5);   // src lane: group (g&1)*2
        const int A1 = A0 + 16;
        const unsigned int s00 = __shfl(pk0[0], A0), s01 = __shfl(pk0[1], A0);
        const unsigned int s02 = __shfl(pk0[0], A1), s03 = __shfl(pk0[1], A1);
        const unsigned int s10 = __shfl(pk1[0], A0), s11 = __shfl(pk1[1], A0);
        const unsigned int s12 = __shfl(pk1[0], A1), s13 = __shfl(pk1[1], A1);
        const bool hk = (g >> 1);             // which kc this lane needs
        union U { unsigned int w[4]; bf16x8 v; } pa;
        pa.w[0] = hk ? s10 : s00;  pa.w[1] = hk ? s11 : s01;
        pa.w[2] = hk ? s12 : s02;  pa.w[3] = hk ? s13 : s03;

        // ---- O^T += Vt-frag x P^T : 16 d-chunks (T5: setprio) ----
        __builtin_amdgcn_s_setprio(1);
        #pragma unroll
        for (int dc = 0; dc < 16; ++dc) {
            bf16x8 vf = *(const bf16x8*)(Vsb + (dc * 16 + qi) * 64 + vsw);
            o[dc] = __builtin_amdgcn_mfma_f32_16x16x32_bf16(vf, pa.v, o[dc], 0, 0, 0);
        }
        __builtin_amdgcn_s_setprio(0);

        __syncthreads();   // implicit vmcnt(0): tile s+1 DMAs complete
        p ^= 1;
    }

    // ---- merge across key halves (per-lane scalar state) ----
    const int qidx = rg * 16 + qi;            // block-local row
    if (g == 0) Mbuf[qidx * 2 + kh] = m0;
    __syncthreads();

    {
        const float gm = fmaxf(Mbuf[qidx * 2], Mbuf[qidx * 2 + 1]);
        const float corr = exp2f((m0 - gm) * C);
        l0 *= corr;
        #pragma unroll
        for (int dc = 0; dc < 16; ++dc)
            #pragma unroll
            for (int r = 0; r < 4; ++r) o[dc][r] *= corr;
    }
    if (g == 0) Lbuf[qidx * 2 + kh] = l0;

    float* Obuf = (float*)smem;               // [64][260], aliases KV buffers
    if (kh == 1) {
        #pragma unroll
        for (int dc = 0; dc < 16; ++dc)
            #pragma unroll
            for (int r = 0; r < 4; ++r)
                Obuf[qidx * 260 + dc * 16 + 4 * g + r] = o[dc][r];
    }
    __syncthreads();

    if (kh == 0) {
        const float inv = 1.0f / (Lbuf[qidx * 2] + Lbuf[qidx * 2 + 1]);
        #pragma unroll
        for (int dc = 0; dc < 16; ++dc)
            #pragma unroll
            for (int r = 0; r < 4; ++r) {
                const int d = dc * 16 + 4 * g + r;
                Out[(size_t)(q0 + qi) * D_ + d] =
                    (o[dc][r] + Obuf[qidx * 260 + d]) * inv;
            }
    }
}

extern "C" void kernel_launch(void* const* d_in, const int* in_sizes, int n_in,
                              void* d_out, int out_size, void* d_ws, size_t ws_size,
                              hipStream_t stream) {
    (void)out_size; (void)ws_size;
    const void *Xp = nullptr, *Wp = nullptr, *bp = nullptr;
    for (int i = 0; i < n_in; ++i) {
        if      (in_sizes[i] == B_ * S_ * D_) Xp = d_in[i];
        else if (in_sizes[i] == 3 * D_ * D_)  Wp = d_in[i];
        else if (in_sizes[i] == 3 * D_)       bp = d_in[i];
    }
    if (!Xp) Xp = d_in[0];
    if (!Wp) Wp = d_in[1];
    if (!bp) bp = d_in[2];

    float* Out = (float*)d_out;                                 // [B*S][256] f32

    unsigned short* Qb = (unsigned short*)d_ws;                 // 8 MiB
    unsigned short* Kb = Qb + (size_t)B_ * S_ * D_;             // 8 MiB
    unsigned short* Vt = Kb + (size_t)B_ * S_ * D_;             // 8 MiB
    // ws needed: 24 MiB

    dim3 pgrid(128, 6);   // M/128 x E/128
    qkv_proj<<<pgrid, 256, 0, stream>>>((const float*)Xp, (const float*)Wp,
                                        (const float*)bp, Qb, Kb, Vt);
    attn_fwd<<<256, 512, 0, stream>>>(Qb, Kb, Vt, Out);
}